// Round 11
// baseline (2259.407 us; speedup 1.0000x reference)
//
#include <hip/hip_runtime.h>

// Wave-level LDS ordering fence for the few remaining LDS phase transitions.
#define FENCE() asm volatile("s_waitcnt lgkmcnt(0)" ::: "memory")

typedef float v2f   __attribute__((ext_vector_type(2)));
typedef float f32x4 __attribute__((ext_vector_type(4)));

__device__ __forceinline__ float fshfl_xor(float v, int m) { return __shfl_xor(v, m, 64); }
__device__ __forceinline__ float fshfl(float v, int s)     { return __shfl(v, s, 64); }
__device__ __forceinline__ float fsqrt(float x) { return __builtin_amdgcn_sqrtf(x); }
__device__ __forceinline__ float frcp (float x) { return __builtin_amdgcn_rcpf(x); }
__device__ __forceinline__ float frsq (float x) { return __builtin_amdgcn_rsqf(x); }
__device__ __forceinline__ v2f   fma2(v2f a, v2f b, v2f c)       { return __builtin_elementwise_fma(a, b, c); }
__device__ __forceinline__ f32x4 fma4(f32x4 a, f32x4 b, f32x4 c) { return __builtin_elementwise_fma(a, b, c); }

// One block = 256 threads = 4 waves, one 32x32 SPD matrix per wave.
// r11 = r10's register-resident Jacobi with the SCRATCH SPILL fixed:
// r10 punned float[16] arrays through (v2f*)/(float*) casts and runtime-
// indexed v1r[i] under partial unroll -> SROA failed -> arrays demoted to
// scratch (WRITE_SIZE 2.3MB -> 395MB, VGPR "32"). All local state is now
// native v2f/f32x4 variables with fully-static component access; casts only
// on LDS/global pointers. launch_bounds(256,4) so the register allocator is
// never forced to spill (<=128 VGPR; if usage <=64 HW still runs 8 blocks/CU).
// LDS: 4*1152*4 = 18432 B/block.
#define PT_S 34
__global__ __launch_bounds__(256, 4) void spd_fused(
    const float* __restrict__ xg,
    const float* __restrict__ w1g,
    const float* __restrict__ w2g,
    const float* __restrict__ w3g,
    const float* __restrict__ fcg,
    float* __restrict__ outg,
    int B)
{
  __shared__ float slot[4][1152];

  const int tid  = threadIdx.x;
  const int wid  = tid >> 6;
  const int lane = tid & 63;

  float* Cc = slot[wid];          // x (stride 32) -> M1 cols (stride 36) -> Qb/J scratch
  float* Pt = slot[wid] + 576;    // Ps transposed [16][PT_S], in dead M1 space

  const long b = (long)blockIdx.x * 4 + wid;
  if (b >= B) return;

  // ---------------- load x -> Cc row-major [32][32] (stride 32)
  {
    const f32x4* xv = (const f32x4*)(xg + (size_t)b * 1024);
    f32x4* c4 = (f32x4*)Cc;
    #pragma unroll
    for (int jj = 0; jj < 4; ++jj) {
      int i4 = lane + 64 * jj;
      c4[i4] = xv[i4];
    }
  }
  FENCE();

  const int j = lane & 31;
  const int h = lane >> 5;

  // ---------------- Tmat = x * w1 in registers (packed). T2[e] = rows
  // {16h+2e, +1} of column j. Uses x symmetry: read x rows as f32x4.
  v2f T2[8];
  {
    #pragma unroll
    for (int e = 0; e < 8; ++e) T2[e] = (v2f){0.f, 0.f};
    const f32x4* c4 = (const f32x4*)Cc;
    #pragma unroll 4
    for (int c = 0; c < 32; ++c) {
      float wv = w1g[c * 32 + j];
      v2f wv2 = {wv, wv};
      f32x4 x0 = c4[c * 8 + h * 4 + 0];
      f32x4 x1 = c4[c * 8 + h * 4 + 1];
      f32x4 x2 = c4[c * 8 + h * 4 + 2];
      f32x4 x3 = c4[c * 8 + h * 4 + 3];
      T2[0] = fma2(x0.lo, wv2, T2[0]); T2[1] = fma2(x0.hi, wv2, T2[1]);
      T2[2] = fma2(x1.lo, wv2, T2[2]); T2[3] = fma2(x1.hi, wv2, T2[3]);
      T2[4] = fma2(x2.lo, wv2, T2[4]); T2[5] = fma2(x2.hi, wv2, T2[5]);
      T2[6] = fma2(x3.lo, wv2, T2[6]); T2[7] = fma2(x3.hi, wv2, T2[7]);
    }
  }
  FENCE();   // all x reads complete before M1 overwrites Cc

  // ---------------- M1 = w1^T * Tmat -> Cc linear column-major, stride 36.
  {
    const f32x4* w14 = (const f32x4*)w1g;   // row r = w14[r*8 + 0..7]
    #pragma unroll
    for (int ih2 = 0; ih2 < 4; ++ih2) {     // output rows 8*ih2 .. 8*ih2+7
      f32x4 A = {0.f, 0.f, 0.f, 0.f};
      f32x4 Bv = {0.f, 0.f, 0.f, 0.f};
      #pragma unroll
      for (int e = 0; e < 16; ++e) {
        int r = 16 * h + e;
        float tv = T2[e >> 1][e & 1];
        f32x4 tv4 = {tv, tv, tv, tv};
        A  = fma4(w14[r * 8 + ih2 * 2],     tv4, A);
        Bv = fma4(w14[r * 8 + ih2 * 2 + 1], tv4, Bv);
      }
      A.x += fshfl_xor(A.x, 32);  A.y += fshfl_xor(A.y, 32);
      A.z += fshfl_xor(A.z, 32);  A.w += fshfl_xor(A.w, 32);
      Bv.x += fshfl_xor(Bv.x, 32); Bv.y += fshfl_xor(Bv.y, 32);
      Bv.z += fshfl_xor(Bv.z, 32); Bv.w += fshfl_xor(Bv.w, 32);
      if (h == (ih2 & 1)) {
        *(f32x4*)(Cc + j * 36 + ih2 * 8)     = A;
        *(f32x4*)(Cc + j * 36 + ih2 * 8 + 4) = Bv;
      }
    }
  }
  FENCE();

  // ---------------- load own column half into v2f registers (one-time)
  v2f v1[8];
  {
    const float* bp = Cc + j * 36 + (h << 4);
    f32x4 q0 = *(const f32x4*)(bp);
    f32x4 q1 = *(const f32x4*)(bp + 4);
    f32x4 q2 = *(const f32x4*)(bp + 8);
    f32x4 q3 = *(const f32x4*)(bp + 12);
    v1[0] = q0.lo; v1[1] = q0.hi; v1[2] = q1.lo; v1[3] = q1.hi;
    v1[4] = q2.lo; v1[5] = q2.hi; v1[6] = q3.lo; v1[7] = q3.hi;
  }

  // ---------------- one-sided Jacobi, n=32, fully register-resident.
  {
    const int hb = lane & 32;     // half bit (0 / 32)
    #pragma unroll 1
    for (int sweep = 0; sweep < 8; ++sweep) {
      float offmax = 0.f;
      #pragma unroll 1
      for (int r = 0; r < 31; ++r) {
        int d = 2 * r - j;
        d += (d >> 31) & 31;
        if (d >= 31) d -= 31;
        const int m = (j == 31) ? r : ((j == r) ? 31 : d);
        const int mlane = m | hb;
        v2f uu[8];
        #pragma unroll
        for (int i = 0; i < 8; ++i) {
          uu[i].x = fshfl(v1[i].x, mlane);
          uu[i].y = fshfl(v1[i].y, mlane);
        }
        v2f s2a = {0.f, 0.f}, s2b = {0.f, 0.f}, s2g = {0.f, 0.f};
        #pragma unroll
        for (int i = 0; i < 8; ++i) {
          s2a = fma2(v1[i], v1[i], s2a);
          s2b = fma2(uu[i], uu[i], s2b);
          s2g = fma2(v1[i], uu[i], s2g);
        }
        float sa = s2a.x + s2a.y;
        float sb = s2b.x + s2b.y;
        float sg = s2g.x + s2g.y;
        sa += fshfl_xor(sa, 32);
        sb += fshfl_xor(sb, 32);
        sg += fshfl_xor(sg, 32);
        const bool isp = j < m;
        float nA = isp ? sa : sb;
        float nB = isp ? sb : sa;
        float rel = sg * sg * frcp(fmaxf(nA * nB, 1e-30f));
        offmax = fmaxf(offmax, rel);
        if (rel > 1e-13f) {
          float uc = 0.5f * (nB - nA);
          float R  = fsqrt(uc * uc + sg * sg);
          float t  = sg * frcp(uc + ((uc >= 0.f) ? R : -R));
          float ct = frsq(1.f + t * t);
          float st = ct * t;
          float s  = isp ? -st : st;
          v2f ct2 = {ct, ct}, sv2 = {s, s};
          #pragma unroll
          for (int i = 0; i < 8; ++i)
            v1[i] = fma2(uu[i], sv2, v1[i] * ct2);
        }
      }
      #pragma unroll
      for (int mm = 1; mm <= 32; mm <<= 1) offmax = fmaxf(offmax, fshfl_xor(offmax, mm));
      if (offmax < 1e-11f) break;
    }
  }

  // ---------------- lambda_1 + ReEig + Ps = sqrt(clamp(lam1))*v1hat^T w2,
  // all from registers; Pt[16][PT_S] written transposed (conflict-free).
  {
    v2f ssv = {0.f, 0.f};
    #pragma unroll
    for (int i = 0; i < 8; ++i) ssv = fma2(v1[i], v1[i], ssv);
    float ss = ssv.x + ssv.y;
    ss += fshfl_xor(ss, 32);
    float lam = fsqrt(ss);
    float sc1 = (lam > 0.f) ? (fsqrt(fmaxf(lam, 1e-4f)) * frcp(lam)) : 0.f;
    f32x4 acc0 = {0.f,0.f,0.f,0.f}, acc1 = acc0, acc2 = acc0, acc3 = acc0;
    #pragma unroll
    for (int t = 0; t < 8; ++t) {
      int rr = (h << 4) + 2 * t;
      const f32x4* wr0 = (const f32x4*)(w2g + rr * 16);
      const f32x4* wr1 = (const f32x4*)(w2g + (rr + 1) * 16);
      float vx = v1[t].x, vy = v1[t].y;
      f32x4 vx4 = {vx, vx, vx, vx};
      f32x4 vy4 = {vy, vy, vy, vy};
      acc0 = fma4(wr0[0], vx4, acc0); acc1 = fma4(wr0[1], vx4, acc1);
      acc2 = fma4(wr0[2], vx4, acc2); acc3 = fma4(wr0[3], vx4, acc3);
      acc0 = fma4(wr1[0], vy4, acc0); acc1 = fma4(wr1[1], vy4, acc1);
      acc2 = fma4(wr1[2], vy4, acc2); acc3 = fma4(wr1[3], vy4, acc3);
    }
    acc0.x = (acc0.x + fshfl_xor(acc0.x, 32)) * sc1;
    acc0.y = (acc0.y + fshfl_xor(acc0.y, 32)) * sc1;
    acc0.z = (acc0.z + fshfl_xor(acc0.z, 32)) * sc1;
    acc0.w = (acc0.w + fshfl_xor(acc0.w, 32)) * sc1;
    acc1.x = (acc1.x + fshfl_xor(acc1.x, 32)) * sc1;
    acc1.y = (acc1.y + fshfl_xor(acc1.y, 32)) * sc1;
    acc1.z = (acc1.z + fshfl_xor(acc1.z, 32)) * sc1;
    acc1.w = (acc1.w + fshfl_xor(acc1.w, 32)) * sc1;
    acc2.x = (acc2.x + fshfl_xor(acc2.x, 32)) * sc1;
    acc2.y = (acc2.y + fshfl_xor(acc2.y, 32)) * sc1;
    acc2.z = (acc2.z + fshfl_xor(acc2.z, 32)) * sc1;
    acc2.w = (acc2.w + fshfl_xor(acc2.w, 32)) * sc1;
    acc3.x = (acc3.x + fshfl_xor(acc3.x, 32)) * sc1;
    acc3.y = (acc3.y + fshfl_xor(acc3.y, 32)) * sc1;
    acc3.z = (acc3.z + fshfl_xor(acc3.z, 32)) * sc1;
    acc3.w = (acc3.w + fshfl_xor(acc3.w, 32)) * sc1;
    // lane (j,h) stores Ps[j][8h..8h+7]: h=0 -> acc0/acc1, h=1 -> acc2/acc3
    f32x4 lo = h ? acc2 : acc0;
    f32x4 hi = h ? acc3 : acc1;
    const int jb8 = h << 3;
    Pt[(jb8 + 0) * PT_S + j] = lo.x;
    Pt[(jb8 + 1) * PT_S + j] = lo.y;
    Pt[(jb8 + 2) * PT_S + j] = lo.z;
    Pt[(jb8 + 3) * PT_S + j] = lo.w;
    Pt[(jb8 + 4) * PT_S + j] = hi.x;
    Pt[(jb8 + 5) * PT_S + j] = hi.y;
    Pt[(jb8 + 6) * PT_S + j] = hi.z;
    Pt[(jb8 + 7) * PT_S + j] = hi.w;
  }
  FENCE();

  // ---------------- M2 = Ps^T Ps directly into stage-2 registers.
  // lane = c2 + 16*h4 owns rows 4h4..4h4+3 of M2 column c2.
  const int c2 = lane & 15;
  const int h4 = lane >> 4;
  f32x4 v2r;
  {
    v2f a0 = {0.f,0.f}, a1 = {0.f,0.f}, a2 = {0.f,0.f}, a3 = {0.f,0.f};
    #pragma unroll 2
    for (int kk = 0; kk < 32; kk += 4) {
      f32x4 aa = *(const f32x4*)(Pt + c2 * PT_S + kk);
      f32x4 b0 = *(const f32x4*)(Pt + (4 * h4 + 0) * PT_S + kk);
      f32x4 b1 = *(const f32x4*)(Pt + (4 * h4 + 1) * PT_S + kk);
      f32x4 b2 = *(const f32x4*)(Pt + (4 * h4 + 2) * PT_S + kk);
      f32x4 b3 = *(const f32x4*)(Pt + (4 * h4 + 3) * PT_S + kk);
      a0 = fma2(aa.lo, b0.lo, a0); a0 = fma2(aa.hi, b0.hi, a0);
      a1 = fma2(aa.lo, b1.lo, a1); a1 = fma2(aa.hi, b1.hi, a1);
      a2 = fma2(aa.lo, b2.lo, a2); a2 = fma2(aa.hi, b2.hi, a2);
      a3 = fma2(aa.lo, b3.lo, a3); a3 = fma2(aa.hi, b3.hi, a3);
    }
    v2r.x = a0.x + a0.y;
    v2r.y = a1.x + a1.y;
    v2r.z = a2.x + a2.y;
    v2r.w = a3.x + a3.y;
  }

  // ---------------- one-sided Jacobi, n=16, register-resident.
  {
    const int h4b = lane & 48;    // h4*16 bits
    #pragma unroll 1
    for (int sweep = 0; sweep < 6; ++sweep) {
      float offmax = 0.f;
      #pragma unroll 1
      for (int r = 0; r < 15; ++r) {
        int d = 2 * r - c2;
        d += (d >> 31) & 15;
        if (d >= 15) d -= 15;
        const int m = (c2 == 15) ? r : ((c2 == r) ? 15 : d);
        const int mlane = m | h4b;
        float u0 = fshfl(v2r.x, mlane);
        float u1 = fshfl(v2r.y, mlane);
        float u2 = fshfl(v2r.z, mlane);
        float u3 = fshfl(v2r.w, mlane);
        v2f va = {v2r.x, v2r.y}, vb = {v2r.z, v2r.w};
        v2f ua = {u0, u1},       ub = {u2, u3};
        v2f s2a = fma2(vb, vb, va * va);
        v2f s2b = fma2(ub, ub, ua * ua);
        v2f s2g = fma2(vb, ub, va * ua);
        float sa = s2a.x + s2a.y;
        float sb = s2b.x + s2b.y;
        float sg = s2g.x + s2g.y;
        sa += fshfl_xor(sa, 16); sa += fshfl_xor(sa, 32);
        sb += fshfl_xor(sb, 16); sb += fshfl_xor(sb, 32);
        sg += fshfl_xor(sg, 16); sg += fshfl_xor(sg, 32);
        const bool isp = c2 < m;
        float nA = isp ? sa : sb;
        float nB = isp ? sb : sa;
        float rel = sg * sg * frcp(fmaxf(nA * nB, 1e-30f));
        offmax = fmaxf(offmax, rel);
        if (rel > 1e-13f) {
          float uc = 0.5f * (nB - nA);
          float R  = fsqrt(uc * uc + sg * sg);
          float t  = sg * frcp(uc + ((uc >= 0.f) ? R : -R));
          float ct = frsq(1.f + t * t);
          float st = ct * t;
          float s  = isp ? -st : st;
          v2r.x = ct * v2r.x + s * u0;
          v2r.y = ct * v2r.y + s * u1;
          v2r.z = ct * v2r.z + s * u2;
          v2r.w = ct * v2r.w + s * u3;
        }
      }
      #pragma unroll
      for (int mm = 1; mm <= 32; mm <<= 1) offmax = fmaxf(offmax, fshfl_xor(offmax, mm));
      if (offmax < 1e-11f) break;
    }
  }

  // ---------------- Qb row c2 = (V2^T w3)[c2][:] * sqrt(clamp(lam2)) from regs
  {
    f32x4 qq = {0.f, 0.f, 0.f, 0.f};
    f32x4 w0 = *(const f32x4*)(w3g + (4 * h4 + 0) * 4);
    f32x4 w1r = *(const f32x4*)(w3g + (4 * h4 + 1) * 4);
    f32x4 w2r = *(const f32x4*)(w3g + (4 * h4 + 2) * 4);
    f32x4 w3r = *(const f32x4*)(w3g + (4 * h4 + 3) * 4);
    f32x4 vv0 = {v2r.x, v2r.x, v2r.x, v2r.x};
    f32x4 vv1 = {v2r.y, v2r.y, v2r.y, v2r.y};
    f32x4 vv2 = {v2r.z, v2r.z, v2r.z, v2r.z};
    f32x4 vv3 = {v2r.w, v2r.w, v2r.w, v2r.w};
    qq = fma4(w0, vv0, qq); qq = fma4(w1r, vv1, qq);
    qq = fma4(w2r, vv2, qq); qq = fma4(w3r, vv3, qq);
    v2f sp = fma2(v2r.hi, v2r.hi, v2r.lo * v2r.lo);
    float ssp = sp.x + sp.y;
    float q0 = qq.x, q1 = qq.y, q2 = qq.z, q3 = qq.w;
    q0 += fshfl_xor(q0, 16); q0 += fshfl_xor(q0, 32);
    q1 += fshfl_xor(q1, 16); q1 += fshfl_xor(q1, 32);
    q2 += fshfl_xor(q2, 16); q2 += fshfl_xor(q2, 32);
    q3 += fshfl_xor(q3, 16); q3 += fshfl_xor(q3, 32);
    ssp += fshfl_xor(ssp, 16); ssp += fshfl_xor(ssp, 32);
    float lam = fsqrt(ssp);
    float scl = (lam > 0.f) ? (frcp(lam) * fsqrt(fmaxf(lam, 1e-4f))) : 0.f;
    if (h4 == 0)
      *(f32x4*)(Cc + c2 * 4) = (f32x4){q0 * scl, q1 * scl, q2 * scl, q3 * scl};
  }
  FENCE();

  // ---------------- stage 3: one-sided Jacobi ON THE 16x4 FACTOR, with
  // accumulated rotations J (eigenvectors of M3 = Q^T Q). 5 sweeps.
  float qv = Cc[lane];            // Qb[kq][jq], kq*4+jq == lane
  const int kq = lane >> 2;
  const int jq = lane & 3;
  float jv = (kq == jq) ? 1.f : 0.f;
  {
    #define ROT3(P_, Q_) do {                                             \
      float w_ = fshfl_xor(qv, (P_) ^ (Q_));                              \
      float s1 = qv * qv, s2 = w_ * w_, s3 = qv * w_;                     \
      s1 += fshfl_xor(s1, 4);  s2 += fshfl_xor(s2, 4);  s3 += fshfl_xor(s3, 4);  \
      s1 += fshfl_xor(s1, 8);  s2 += fshfl_xor(s2, 8);  s3 += fshfl_xor(s3, 8);  \
      s1 += fshfl_xor(s1, 16); s2 += fshfl_xor(s2, 16); s3 += fshfl_xor(s3, 16); \
      s1 += fshfl_xor(s1, 32); s2 += fshfl_xor(s2, 32); s3 += fshfl_xor(s3, 32); \
      bool isp = (jq == (P_)), isq = (jq == (Q_));                        \
      float sa = isp ? s1 : s2;                                           \
      float sb = isp ? s2 : s1;                                           \
      float u_ = 0.5f * (sb - sa);                                        \
      float R_ = fsqrt(u_ * u_ + s3 * s3);                                \
      float dn_ = u_ + copysignf(fmaxf(R_, 1e-30f), u_);                  \
      float t_ = s3 * frcp(dn_);                                          \
      float ct = frsq(1.f + t_ * t_);                                     \
      float st = ct * t_;                                                 \
      float wj_ = fshfl_xor(jv, (P_) ^ (Q_));                             \
      float nv  = isp ? (ct * qv - st * w_)  : (st * w_  + ct * qv);      \
      float nvj = isp ? (ct * jv - st * wj_) : (st * wj_ + ct * jv);      \
      if (isp | isq) { qv = nv; jv = nvj; }                               \
    } while (0)

    #pragma unroll 1
    for (int sweep = 0; sweep < 5; ++sweep) {
      ROT3(0,1); ROT3(2,3); ROT3(0,2); ROT3(1,3); ROT3(0,3); ROT3(1,2);
    }
    #undef ROT3
  }

  // ---------------- lambda_3 = ||col||^2, LogEig via J, FC, log_softmax
  {
    float ss = qv * qv;
    ss += fshfl_xor(ss, 4); ss += fshfl_xor(ss, 8);
    ss += fshfl_xor(ss, 16); ss += fshfl_xor(ss, 32);
    float lwv = logf(fmaxf(ss, 1e-10f));       // log eigenvalue of column jq
    if (kq < 4)  Cc[64 + kq * 4 + jq] = jv;    // J, row-major 4x4
    if (kq == 0) Cc[80 + jq] = lwv;            // lanes 0..3: per-column loglam
    FENCE();

    float f = 0.f;
    if (lane < 16) {
      int i3 = lane >> 2, j3 = lane & 3;
      #pragma unroll
      for (int c = 0; c < 4; ++c)
        f += Cc[80 + c] * Cc[64 + i3 * 4 + c] * Cc[64 + j3 * 4 + c];
    }
    float t0 = 0.f, t1 = 0.f;
    if (lane < 16) { t0 = f * fcg[2 * lane]; t1 = f * fcg[2 * lane + 1]; }
    t0 += fshfl_xor(t0, 1); t1 += fshfl_xor(t1, 1);
    t0 += fshfl_xor(t0, 2); t1 += fshfl_xor(t1, 2);
    t0 += fshfl_xor(t0, 4); t1 += fshfl_xor(t1, 4);
    t0 += fshfl_xor(t0, 8); t1 += fshfl_xor(t1, 8);
    float mx  = fmaxf(t0, t1);
    float lse = mx + logf(expf(t0 - mx) + expf(t1 - mx));

    float* outFeat = outg + (size_t)B * 2;
    if (lane < 16) outFeat[(size_t)b * 16 + lane] = f;
    if (lane < 2)  outg[(size_t)b * 2 + lane] = (lane == 0 ? t0 : t1) - lse;
  }
}

extern "C" void kernel_launch(void* const* d_in, const int* in_sizes, int n_in,
                              void* d_out, int out_size, void* d_ws, size_t ws_size,
                              hipStream_t stream) {
  const float* x  = (const float*)d_in[0];
  const float* w1 = (const float*)d_in[1];
  const float* w2 = (const float*)d_in[2];
  const float* w3 = (const float*)d_in[3];
  const float* fc = (const float*)d_in[4];
  float* out = (float*)d_out;
  int B = in_sizes[0] / 1024;
  int grid = (B + 3) / 4;
  hipLaunchKernelGGL(spd_fused, dim3(grid), dim3(256), 0, stream,
                     x, w1, w2, w3, fc, out, B);
}

// Round 12
// 2078.100 us; speedup vs baseline: 1.0872x; 1.0872x over previous
//
#include <hip/hip_runtime.h>

// Wave-level LDS ordering fence for the few remaining LDS phase transitions.
#define FENCE() asm volatile("s_waitcnt lgkmcnt(0)" ::: "memory")

typedef float v2f   __attribute__((ext_vector_type(2)));
typedef float f32x4 __attribute__((ext_vector_type(4)));

__device__ __forceinline__ float fshfl_xor(float v, int m) { return __shfl_xor(v, m, 64); }
__device__ __forceinline__ float fsqrt(float x) { return __builtin_amdgcn_sqrtf(x); }
__device__ __forceinline__ float frcp (float x) { return __builtin_amdgcn_rcpf(x); }
__device__ __forceinline__ float frsq (float x) { return __builtin_amdgcn_rsqf(x); }
__device__ __forceinline__ v2f   fma2(v2f a, v2f b, v2f c)       { return __builtin_elementwise_fma(a, b, c); }
__device__ __forceinline__ f32x4 fma4(f32x4 a, f32x4 b, f32x4 c) { return __builtin_elementwise_fma(a, b, c); }

// One block = 256 threads = 4 waves, one 32x32 SPD matrix per wave.
// r12 vs r11 (dur flat 3 rounds; r11: VALU 71%, occ capped 46% by
// launch_bounds arg, WRITE_SIZE clean):
//  - launch_bounds(256,8): measured occupancy tracks the 2nd arg as a CAP
//    (r10 arg8 -> 87%, r11 arg4 -> 46%); VGPR was 60 -> fits 64.
//  - incremental column norms (gesvj-style): after an annihilating rotation
//    the 2x2 Gram eigenvalues are exactly sa - t*sg / sb + t*sg, so ||col||^2
//    lives in a register, refreshed once/sweep; partner norm = 1 shuffle.
//    Cuts 16 of 24 dot pk-FMAs + 2 of 3 reduce shuffles per round.
//  - XOR tournament (hypercube ordering): round mask pairs (j, j^mask),
//    mask = 1..N-1 — all pairs covered; partner lane = lane^mask (1 op).
// Final eigenvalues are still recomputed fresh from columns (lam1/lam2/lam3
// paths untouched). LDS: 4*1152*4 = 18432 B/block.
#define PT_S 34
__global__ __launch_bounds__(256, 8) void spd_fused(
    const float* __restrict__ xg,
    const float* __restrict__ w1g,
    const float* __restrict__ w2g,
    const float* __restrict__ w3g,
    const float* __restrict__ fcg,
    float* __restrict__ outg,
    int B)
{
  __shared__ float slot[4][1152];

  const int tid  = threadIdx.x;
  const int wid  = tid >> 6;
  const int lane = tid & 63;

  float* Cc = slot[wid];          // x (stride 32) -> M1 cols (stride 36) -> Qb/J scratch
  float* Pt = slot[wid] + 576;    // Ps transposed [16][PT_S], in dead M1 space

  const long b = (long)blockIdx.x * 4 + wid;
  if (b >= B) return;

  // ---------------- load x -> Cc row-major [32][32] (stride 32)
  {
    const f32x4* xv = (const f32x4*)(xg + (size_t)b * 1024);
    f32x4* c4 = (f32x4*)Cc;
    #pragma unroll
    for (int jj = 0; jj < 4; ++jj) {
      int i4 = lane + 64 * jj;
      c4[i4] = xv[i4];
    }
  }
  FENCE();

  const int j = lane & 31;
  const int h = lane >> 5;

  // ---------------- Tmat = x * w1 in registers (packed). T2[e] = rows
  // {16h+2e, +1} of column j. Uses x symmetry: read x rows as f32x4.
  v2f T2[8];
  {
    #pragma unroll
    for (int e = 0; e < 8; ++e) T2[e] = (v2f){0.f, 0.f};
    const f32x4* c4 = (const f32x4*)Cc;
    #pragma unroll 4
    for (int c = 0; c < 32; ++c) {
      float wv = w1g[c * 32 + j];
      v2f wv2 = {wv, wv};
      f32x4 x0 = c4[c * 8 + h * 4 + 0];
      f32x4 x1 = c4[c * 8 + h * 4 + 1];
      f32x4 x2 = c4[c * 8 + h * 4 + 2];
      f32x4 x3 = c4[c * 8 + h * 4 + 3];
      T2[0] = fma2(x0.lo, wv2, T2[0]); T2[1] = fma2(x0.hi, wv2, T2[1]);
      T2[2] = fma2(x1.lo, wv2, T2[2]); T2[3] = fma2(x1.hi, wv2, T2[3]);
      T2[4] = fma2(x2.lo, wv2, T2[4]); T2[5] = fma2(x2.hi, wv2, T2[5]);
      T2[6] = fma2(x3.lo, wv2, T2[6]); T2[7] = fma2(x3.hi, wv2, T2[7]);
    }
  }
  FENCE();   // all x reads complete before M1 overwrites Cc

  // ---------------- M1 = w1^T * Tmat -> Cc linear column-major, stride 36.
  {
    const f32x4* w14 = (const f32x4*)w1g;   // row r = w14[r*8 + 0..7]
    #pragma unroll
    for (int ih2 = 0; ih2 < 4; ++ih2) {     // output rows 8*ih2 .. 8*ih2+7
      f32x4 A = {0.f, 0.f, 0.f, 0.f};
      f32x4 Bv = {0.f, 0.f, 0.f, 0.f};
      #pragma unroll
      for (int e = 0; e < 16; ++e) {
        int r = 16 * h + e;
        float tv = T2[e >> 1][e & 1];
        f32x4 tv4 = {tv, tv, tv, tv};
        A  = fma4(w14[r * 8 + ih2 * 2],     tv4, A);
        Bv = fma4(w14[r * 8 + ih2 * 2 + 1], tv4, Bv);
      }
      A.x += fshfl_xor(A.x, 32);  A.y += fshfl_xor(A.y, 32);
      A.z += fshfl_xor(A.z, 32);  A.w += fshfl_xor(A.w, 32);
      Bv.x += fshfl_xor(Bv.x, 32); Bv.y += fshfl_xor(Bv.y, 32);
      Bv.z += fshfl_xor(Bv.z, 32); Bv.w += fshfl_xor(Bv.w, 32);
      if (h == (ih2 & 1)) {
        *(f32x4*)(Cc + j * 36 + ih2 * 8)     = A;
        *(f32x4*)(Cc + j * 36 + ih2 * 8 + 4) = Bv;
      }
    }
  }
  FENCE();

  // ---------------- load own column half into v2f registers (one-time)
  v2f v1[8];
  {
    const float* bp = Cc + j * 36 + (h << 4);
    f32x4 q0 = *(const f32x4*)(bp);
    f32x4 q1 = *(const f32x4*)(bp + 4);
    f32x4 q2 = *(const f32x4*)(bp + 8);
    f32x4 q3 = *(const f32x4*)(bp + 12);
    v1[0] = q0.lo; v1[1] = q0.hi; v1[2] = q1.lo; v1[3] = q1.hi;
    v1[4] = q2.lo; v1[5] = q2.hi; v1[6] = q3.lo; v1[7] = q3.hi;
  }

  // ---------------- one-sided Jacobi, n=32, register-resident, XOR
  // tournament, incremental norms (refreshed each sweep).
  {
    #pragma unroll 1
    for (int sweep = 0; sweep < 8; ++sweep) {
      // fresh own-norm (kills incremental drift)
      v2f s2n = {0.f, 0.f};
      #pragma unroll
      for (int i = 0; i < 8; ++i) s2n = fma2(v1[i], v1[i], s2n);
      float sn = s2n.x + s2n.y;
      sn += fshfl_xor(sn, 32);

      float offmax = 0.f;
      #pragma unroll 1
      for (int mask = 1; mask < 32; ++mask) {
        const int m = j ^ mask;
        v2f uu[8];
        #pragma unroll
        for (int i = 0; i < 8; ++i) {
          uu[i].x = fshfl_xor(v1[i].x, mask);
          uu[i].y = fshfl_xor(v1[i].y, mask);
        }
        float sb_o = fshfl_xor(sn, mask);    // partner's maintained norm
        v2f sgv = {0.f, 0.f};
        #pragma unroll
        for (int i = 0; i < 8; ++i) sgv = fma2(v1[i], uu[i], sgv);
        float sg = sgv.x + sgv.y;
        sg += fshfl_xor(sg, 32);
        const bool isp = j < m;
        float nA = isp ? sn : sb_o;
        float nB = isp ? sb_o : sn;
        float rel = sg * sg * frcp(fmaxf(nA * nB, 1e-30f));
        offmax = fmaxf(offmax, rel);
        if (rel > 1e-13f) {
          float uc = 0.5f * (nB - nA);
          float R  = fsqrt(uc * uc + sg * sg);
          float t  = sg * frcp(uc + ((uc >= 0.f) ? R : -R));
          float ct = frsq(1.f + t * t);
          float st = ct * t;
          float s  = isp ? -st : st;
          v2f ct2 = {ct, ct}, sv2 = {s, s};
          #pragma unroll
          for (int i = 0; i < 8; ++i)
            v1[i] = fma2(uu[i], sv2, v1[i] * ct2);
          // 2x2 Gram eigenvalue identity: a' = nA - t*sg, b' = nB + t*sg
          sn = fmaxf(isp ? (nA - t * sg) : (nB + t * sg), 0.f);
        }
      }
      #pragma unroll
      for (int mm = 1; mm <= 32; mm <<= 1) offmax = fmaxf(offmax, fshfl_xor(offmax, mm));
      if (offmax < 1e-11f) break;
    }
  }

  // ---------------- lambda_1 + ReEig + Ps = sqrt(clamp(lam1))*v1hat^T w2,
  // all from registers (fresh norm); Pt[16][PT_S] transposed (conflict-free).
  {
    v2f ssv = {0.f, 0.f};
    #pragma unroll
    for (int i = 0; i < 8; ++i) ssv = fma2(v1[i], v1[i], ssv);
    float ss = ssv.x + ssv.y;
    ss += fshfl_xor(ss, 32);
    float lam = fsqrt(ss);
    float sc1 = (lam > 0.f) ? (fsqrt(fmaxf(lam, 1e-4f)) * frcp(lam)) : 0.f;
    f32x4 acc0 = {0.f,0.f,0.f,0.f}, acc1 = acc0, acc2 = acc0, acc3 = acc0;
    #pragma unroll
    for (int t = 0; t < 8; ++t) {
      int rr = (h << 4) + 2 * t;
      const f32x4* wr0 = (const f32x4*)(w2g + rr * 16);
      const f32x4* wr1 = (const f32x4*)(w2g + (rr + 1) * 16);
      float vx = v1[t].x, vy = v1[t].y;
      f32x4 vx4 = {vx, vx, vx, vx};
      f32x4 vy4 = {vy, vy, vy, vy};
      acc0 = fma4(wr0[0], vx4, acc0); acc1 = fma4(wr0[1], vx4, acc1);
      acc2 = fma4(wr0[2], vx4, acc2); acc3 = fma4(wr0[3], vx4, acc3);
      acc0 = fma4(wr1[0], vy4, acc0); acc1 = fma4(wr1[1], vy4, acc1);
      acc2 = fma4(wr1[2], vy4, acc2); acc3 = fma4(wr1[3], vy4, acc3);
    }
    acc0.x = (acc0.x + fshfl_xor(acc0.x, 32)) * sc1;
    acc0.y = (acc0.y + fshfl_xor(acc0.y, 32)) * sc1;
    acc0.z = (acc0.z + fshfl_xor(acc0.z, 32)) * sc1;
    acc0.w = (acc0.w + fshfl_xor(acc0.w, 32)) * sc1;
    acc1.x = (acc1.x + fshfl_xor(acc1.x, 32)) * sc1;
    acc1.y = (acc1.y + fshfl_xor(acc1.y, 32)) * sc1;
    acc1.z = (acc1.z + fshfl_xor(acc1.z, 32)) * sc1;
    acc1.w = (acc1.w + fshfl_xor(acc1.w, 32)) * sc1;
    acc2.x = (acc2.x + fshfl_xor(acc2.x, 32)) * sc1;
    acc2.y = (acc2.y + fshfl_xor(acc2.y, 32)) * sc1;
    acc2.z = (acc2.z + fshfl_xor(acc2.z, 32)) * sc1;
    acc2.w = (acc2.w + fshfl_xor(acc2.w, 32)) * sc1;
    acc3.x = (acc3.x + fshfl_xor(acc3.x, 32)) * sc1;
    acc3.y = (acc3.y + fshfl_xor(acc3.y, 32)) * sc1;
    acc3.z = (acc3.z + fshfl_xor(acc3.z, 32)) * sc1;
    acc3.w = (acc3.w + fshfl_xor(acc3.w, 32)) * sc1;
    // lane (j,h) stores Ps[j][8h..8h+7]: h=0 -> acc0/acc1, h=1 -> acc2/acc3
    f32x4 lo = h ? acc2 : acc0;
    f32x4 hi = h ? acc3 : acc1;
    const int jb8 = h << 3;
    Pt[(jb8 + 0) * PT_S + j] = lo.x;
    Pt[(jb8 + 1) * PT_S + j] = lo.y;
    Pt[(jb8 + 2) * PT_S + j] = lo.z;
    Pt[(jb8 + 3) * PT_S + j] = lo.w;
    Pt[(jb8 + 4) * PT_S + j] = hi.x;
    Pt[(jb8 + 5) * PT_S + j] = hi.y;
    Pt[(jb8 + 6) * PT_S + j] = hi.z;
    Pt[(jb8 + 7) * PT_S + j] = hi.w;
  }
  FENCE();

  // ---------------- M2 = Ps^T Ps directly into stage-2 registers.
  // lane = c2 + 16*h4 owns rows 4h4..4h4+3 of M2 column c2.
  const int c2 = lane & 15;
  const int h4 = lane >> 4;
  f32x4 v2r;
  {
    v2f a0 = {0.f,0.f}, a1 = {0.f,0.f}, a2 = {0.f,0.f}, a3 = {0.f,0.f};
    #pragma unroll 2
    for (int kk = 0; kk < 32; kk += 4) {
      f32x4 aa = *(const f32x4*)(Pt + c2 * PT_S + kk);
      f32x4 b0 = *(const f32x4*)(Pt + (4 * h4 + 0) * PT_S + kk);
      f32x4 b1 = *(const f32x4*)(Pt + (4 * h4 + 1) * PT_S + kk);
      f32x4 b2 = *(const f32x4*)(Pt + (4 * h4 + 2) * PT_S + kk);
      f32x4 b3 = *(const f32x4*)(Pt + (4 * h4 + 3) * PT_S + kk);
      a0 = fma2(aa.lo, b0.lo, a0); a0 = fma2(aa.hi, b0.hi, a0);
      a1 = fma2(aa.lo, b1.lo, a1); a1 = fma2(aa.hi, b1.hi, a1);
      a2 = fma2(aa.lo, b2.lo, a2); a2 = fma2(aa.hi, b2.hi, a2);
      a3 = fma2(aa.lo, b3.lo, a3); a3 = fma2(aa.hi, b3.hi, a3);
    }
    v2r.x = a0.x + a0.y;
    v2r.y = a1.x + a1.y;
    v2r.z = a2.x + a2.y;
    v2r.w = a3.x + a3.y;
  }

  // ---------------- one-sided Jacobi, n=16, register-resident, XOR
  // tournament, incremental norms.
  {
    #pragma unroll 1
    for (int sweep = 0; sweep < 6; ++sweep) {
      v2f sp = fma2(v2r.hi, v2r.hi, v2r.lo * v2r.lo);
      float sn2 = sp.x + sp.y;
      sn2 += fshfl_xor(sn2, 16);
      sn2 += fshfl_xor(sn2, 32);
      float offmax = 0.f;
      #pragma unroll 1
      for (int mask = 1; mask < 16; ++mask) {
        const int m = c2 ^ mask;
        float u0 = fshfl_xor(v2r.x, mask);
        float u1 = fshfl_xor(v2r.y, mask);
        float u2 = fshfl_xor(v2r.z, mask);
        float u3 = fshfl_xor(v2r.w, mask);
        float sb_o = fshfl_xor(sn2, mask);
        v2f ua = {u0, u1}, ub = {u2, u3};
        v2f sgv = fma2(v2r.hi, ub, v2r.lo * ua);
        float sg = sgv.x + sgv.y;
        sg += fshfl_xor(sg, 16);
        sg += fshfl_xor(sg, 32);
        const bool isp = c2 < m;
        float nA = isp ? sn2 : sb_o;
        float nB = isp ? sb_o : sn2;
        float rel = sg * sg * frcp(fmaxf(nA * nB, 1e-30f));
        offmax = fmaxf(offmax, rel);
        if (rel > 1e-13f) {
          float uc = 0.5f * (nB - nA);
          float R  = fsqrt(uc * uc + sg * sg);
          float t  = sg * frcp(uc + ((uc >= 0.f) ? R : -R));
          float ct = frsq(1.f + t * t);
          float st = ct * t;
          float s  = isp ? -st : st;
          f32x4 ct4 = {ct, ct, ct, ct};
          f32x4 s4  = {s, s, s, s};
          f32x4 uu4 = {u0, u1, u2, u3};
          v2r = fma4(uu4, s4, v2r * ct4);
          sn2 = fmaxf(isp ? (nA - t * sg) : (nB + t * sg), 0.f);
        }
      }
      #pragma unroll
      for (int mm = 1; mm <= 32; mm <<= 1) offmax = fmaxf(offmax, fshfl_xor(offmax, mm));
      if (offmax < 1e-11f) break;
    }
  }

  // ---------------- Qb row c2 = (V2^T w3)[c2][:] * sqrt(clamp(lam2)) from regs
  {
    f32x4 qq = {0.f, 0.f, 0.f, 0.f};
    f32x4 w0 = *(const f32x4*)(w3g + (4 * h4 + 0) * 4);
    f32x4 w1r = *(const f32x4*)(w3g + (4 * h4 + 1) * 4);
    f32x4 w2r = *(const f32x4*)(w3g + (4 * h4 + 2) * 4);
    f32x4 w3r = *(const f32x4*)(w3g + (4 * h4 + 3) * 4);
    f32x4 vv0 = {v2r.x, v2r.x, v2r.x, v2r.x};
    f32x4 vv1 = {v2r.y, v2r.y, v2r.y, v2r.y};
    f32x4 vv2 = {v2r.z, v2r.z, v2r.z, v2r.z};
    f32x4 vv3 = {v2r.w, v2r.w, v2r.w, v2r.w};
    qq = fma4(w0, vv0, qq); qq = fma4(w1r, vv1, qq);
    qq = fma4(w2r, vv2, qq); qq = fma4(w3r, vv3, qq);
    v2f sp = fma2(v2r.hi, v2r.hi, v2r.lo * v2r.lo);
    float ssp = sp.x + sp.y;
    float q0 = qq.x, q1 = qq.y, q2 = qq.z, q3 = qq.w;
    q0 += fshfl_xor(q0, 16); q0 += fshfl_xor(q0, 32);
    q1 += fshfl_xor(q1, 16); q1 += fshfl_xor(q1, 32);
    q2 += fshfl_xor(q2, 16); q2 += fshfl_xor(q2, 32);
    q3 += fshfl_xor(q3, 16); q3 += fshfl_xor(q3, 32);
    ssp += fshfl_xor(ssp, 16); ssp += fshfl_xor(ssp, 32);
    float lam = fsqrt(ssp);
    float scl = (lam > 0.f) ? (frcp(lam) * fsqrt(fmaxf(lam, 1e-4f))) : 0.f;
    if (h4 == 0)
      *(f32x4*)(Cc + c2 * 4) = (f32x4){q0 * scl, q1 * scl, q2 * scl, q3 * scl};
  }
  FENCE();

  // ---------------- stage 3: one-sided Jacobi ON THE 16x4 FACTOR, with
  // accumulated rotations J (eigenvectors of M3 = Q^T Q). 5 sweeps.
  float qv = Cc[lane];            // Qb[kq][jq], kq*4+jq == lane
  const int kq = lane >> 2;
  const int jq = lane & 3;
  float jv = (kq == jq) ? 1.f : 0.f;
  {
    #define ROT3(P_, Q_) do {                                             \
      float w_ = fshfl_xor(qv, (P_) ^ (Q_));                              \
      float s1 = qv * qv, s2 = w_ * w_, s3 = qv * w_;                     \
      s1 += fshfl_xor(s1, 4);  s2 += fshfl_xor(s2, 4);  s3 += fshfl_xor(s3, 4);  \
      s1 += fshfl_xor(s1, 8);  s2 += fshfl_xor(s2, 8);  s3 += fshfl_xor(s3, 8);  \
      s1 += fshfl_xor(s1, 16); s2 += fshfl_xor(s2, 16); s3 += fshfl_xor(s3, 16); \
      s1 += fshfl_xor(s1, 32); s2 += fshfl_xor(s2, 32); s3 += fshfl_xor(s3, 32); \
      bool isp = (jq == (P_)), isq = (jq == (Q_));                        \
      float sa = isp ? s1 : s2;                                           \
      float sb = isp ? s2 : s1;                                           \
      float u_ = 0.5f * (sb - sa);                                        \
      float R_ = fsqrt(u_ * u_ + s3 * s3);                                \
      float dn_ = u_ + copysignf(fmaxf(R_, 1e-30f), u_);                  \
      float t_ = s3 * frcp(dn_);                                          \
      float ct = frsq(1.f + t_ * t_);                                     \
      float st = ct * t_;                                                 \
      float wj_ = fshfl_xor(jv, (P_) ^ (Q_));                             \
      float nv  = isp ? (ct * qv - st * w_)  : (st * w_  + ct * qv);      \
      float nvj = isp ? (ct * jv - st * wj_) : (st * wj_ + ct * jv);      \
      if (isp | isq) { qv = nv; jv = nvj; }                               \
    } while (0)

    #pragma unroll 1
    for (int sweep = 0; sweep < 5; ++sweep) {
      ROT3(0,1); ROT3(2,3); ROT3(0,2); ROT3(1,3); ROT3(0,3); ROT3(1,2);
    }
    #undef ROT3
  }

  // ---------------- lambda_3 = ||col||^2, LogEig via J, FC, log_softmax
  {
    float ss = qv * qv;
    ss += fshfl_xor(ss, 4); ss += fshfl_xor(ss, 8);
    ss += fshfl_xor(ss, 16); ss += fshfl_xor(ss, 32);
    float lwv = logf(fmaxf(ss, 1e-10f));       // log eigenvalue of column jq
    if (kq < 4)  Cc[64 + kq * 4 + jq] = jv;    // J, row-major 4x4
    if (kq == 0) Cc[80 + jq] = lwv;            // lanes 0..3: per-column loglam
    FENCE();

    float f = 0.f;
    if (lane < 16) {
      int i3 = lane >> 2, j3 = lane & 3;
      #pragma unroll
      for (int c = 0; c < 4; ++c)
        f += Cc[80 + c] * Cc[64 + i3 * 4 + c] * Cc[64 + j3 * 4 + c];
    }
    float t0 = 0.f, t1 = 0.f;
    if (lane < 16) { t0 = f * fcg[2 * lane]; t1 = f * fcg[2 * lane + 1]; }
    t0 += fshfl_xor(t0, 1); t1 += fshfl_xor(t1, 1);
    t0 += fshfl_xor(t0, 2); t1 += fshfl_xor(t1, 2);
    t0 += fshfl_xor(t0, 4); t1 += fshfl_xor(t1, 4);
    t0 += fshfl_xor(t0, 8); t1 += fshfl_xor(t1, 8);
    float mx  = fmaxf(t0, t1);
    float lse = mx + logf(expf(t0 - mx) + expf(t1 - mx));

    float* outFeat = outg + (size_t)B * 2;
    if (lane < 16) outFeat[(size_t)b * 16 + lane] = f;
    if (lane < 2)  outg[(size_t)b * 2 + lane] = (lane == 0 ? t0 : t1) - lse;
  }
}

extern "C" void kernel_launch(void* const* d_in, const int* in_sizes, int n_in,
                              void* d_out, int out_size, void* d_ws, size_t ws_size,
                              hipStream_t stream) {
  const float* x  = (const float*)d_in[0];
  const float* w1 = (const float*)d_in[1];
  const float* w2 = (const float*)d_in[2];
  const float* w3 = (const float*)d_in[3];
  const float* fc = (const float*)d_in[4];
  float* out = (float*)d_out;
  int B = in_sizes[0] / 1024;
  int grid = (B + 3) / 4;
  hipLaunchKernelGGL(spd_fused, dim3(grid), dim3(256), 0, stream,
                     x, w1, w2, w3, fc, out, B);
}

// Round 13
// 2062.148 us; speedup vs baseline: 1.0957x; 1.0077x over previous
//
#include <hip/hip_runtime.h>

// Wave-level LDS ordering fence for the few remaining LDS phase transitions.
#define FENCE() asm volatile("s_waitcnt lgkmcnt(0)" ::: "memory")

typedef float v2f   __attribute__((ext_vector_type(2)));
typedef float f32x4 __attribute__((ext_vector_type(4)));

__device__ __forceinline__ float fshfl_xor(float v, int m) { return __shfl_xor(v, m, 64); }
__device__ __forceinline__ float fsqrt(float x) { return __builtin_amdgcn_sqrtf(x); }
__device__ __forceinline__ float frcp (float x) { return __builtin_amdgcn_rcpf(x); }
__device__ __forceinline__ float frsq (float x) { return __builtin_amdgcn_rsqf(x); }
__device__ __forceinline__ v2f   fma2(v2f a, v2f b, v2f c)       { return __builtin_elementwise_fma(a, b, c); }
__device__ __forceinline__ f32x4 fma4(f32x4 a, f32x4 b, f32x4 c) { return __builtin_elementwise_fma(a, b, c); }

// One block = 256 threads = 4 waves, one 32x32 SPD matrix per wave.
// r13 vs r12: r12's launch_bounds(256,8) capped VGPRs at 64 < peak live set
// (~70) -> allocator spilled arrays to scratch (WRITE_SIZE 476MB, FETCH
// 370MB) even though dur improved via 87% occupancy. r11 showed clean code
// needs ~60-70 VGPRs; occupancy empirically tracks the 2nd launch_bounds arg
// as a cap (8->87%, 4->46%). So: launch_bounds(256,6) -> VGPR budget ~85
// (no spill) at 75% occupancy cap, + unroll-2 on the Ps t-loop to cap
// outstanding w2 loads (the known pressure spike). Algorithms unchanged from
// r12 (XOR tournament + incremental gesvj norms, validated absmax 0.25).
// LDS: 4*1152*4 = 18432 B/block.
#define PT_S 34
__global__ __launch_bounds__(256, 6) void spd_fused(
    const float* __restrict__ xg,
    const float* __restrict__ w1g,
    const float* __restrict__ w2g,
    const float* __restrict__ w3g,
    const float* __restrict__ fcg,
    float* __restrict__ outg,
    int B)
{
  __shared__ float slot[4][1152];

  const int tid  = threadIdx.x;
  const int wid  = tid >> 6;
  const int lane = tid & 63;

  float* Cc = slot[wid];          // x (stride 32) -> M1 cols (stride 36) -> Qb/J scratch
  float* Pt = slot[wid] + 576;    // Ps transposed [16][PT_S], in dead M1 space

  const long b = (long)blockIdx.x * 4 + wid;
  if (b >= B) return;

  // ---------------- load x -> Cc row-major [32][32] (stride 32)
  {
    const f32x4* xv = (const f32x4*)(xg + (size_t)b * 1024);
    f32x4* c4 = (f32x4*)Cc;
    #pragma unroll
    for (int jj = 0; jj < 4; ++jj) {
      int i4 = lane + 64 * jj;
      c4[i4] = xv[i4];
    }
  }
  FENCE();

  const int j = lane & 31;
  const int h = lane >> 5;

  // ---------------- Tmat = x * w1 in registers (packed). T2[e] = rows
  // {16h+2e, +1} of column j. Uses x symmetry: read x rows as f32x4.
  v2f T2[8];
  {
    #pragma unroll
    for (int e = 0; e < 8; ++e) T2[e] = (v2f){0.f, 0.f};
    const f32x4* c4 = (const f32x4*)Cc;
    #pragma unroll 4
    for (int c = 0; c < 32; ++c) {
      float wv = w1g[c * 32 + j];
      v2f wv2 = {wv, wv};
      f32x4 x0 = c4[c * 8 + h * 4 + 0];
      f32x4 x1 = c4[c * 8 + h * 4 + 1];
      f32x4 x2 = c4[c * 8 + h * 4 + 2];
      f32x4 x3 = c4[c * 8 + h * 4 + 3];
      T2[0] = fma2(x0.lo, wv2, T2[0]); T2[1] = fma2(x0.hi, wv2, T2[1]);
      T2[2] = fma2(x1.lo, wv2, T2[2]); T2[3] = fma2(x1.hi, wv2, T2[3]);
      T2[4] = fma2(x2.lo, wv2, T2[4]); T2[5] = fma2(x2.hi, wv2, T2[5]);
      T2[6] = fma2(x3.lo, wv2, T2[6]); T2[7] = fma2(x3.hi, wv2, T2[7]);
    }
  }
  FENCE();   // all x reads complete before M1 overwrites Cc

  // ---------------- M1 = w1^T * Tmat -> Cc linear column-major, stride 36.
  {
    const f32x4* w14 = (const f32x4*)w1g;   // row r = w14[r*8 + 0..7]
    #pragma unroll
    for (int ih2 = 0; ih2 < 4; ++ih2) {     // output rows 8*ih2 .. 8*ih2+7
      f32x4 A = {0.f, 0.f, 0.f, 0.f};
      f32x4 Bv = {0.f, 0.f, 0.f, 0.f};
      #pragma unroll
      for (int e = 0; e < 16; ++e) {
        int r = 16 * h + e;
        float tv = T2[e >> 1][e & 1];
        f32x4 tv4 = {tv, tv, tv, tv};
        A  = fma4(w14[r * 8 + ih2 * 2],     tv4, A);
        Bv = fma4(w14[r * 8 + ih2 * 2 + 1], tv4, Bv);
      }
      A.x += fshfl_xor(A.x, 32);  A.y += fshfl_xor(A.y, 32);
      A.z += fshfl_xor(A.z, 32);  A.w += fshfl_xor(A.w, 32);
      Bv.x += fshfl_xor(Bv.x, 32); Bv.y += fshfl_xor(Bv.y, 32);
      Bv.z += fshfl_xor(Bv.z, 32); Bv.w += fshfl_xor(Bv.w, 32);
      if (h == (ih2 & 1)) {
        *(f32x4*)(Cc + j * 36 + ih2 * 8)     = A;
        *(f32x4*)(Cc + j * 36 + ih2 * 8 + 4) = Bv;
      }
    }
  }
  FENCE();

  // ---------------- load own column half into v2f registers (one-time)
  v2f v1[8];
  {
    const float* bp = Cc + j * 36 + (h << 4);
    f32x4 q0 = *(const f32x4*)(bp);
    f32x4 q1 = *(const f32x4*)(bp + 4);
    f32x4 q2 = *(const f32x4*)(bp + 8);
    f32x4 q3 = *(const f32x4*)(bp + 12);
    v1[0] = q0.lo; v1[1] = q0.hi; v1[2] = q1.lo; v1[3] = q1.hi;
    v1[4] = q2.lo; v1[5] = q2.hi; v1[6] = q3.lo; v1[7] = q3.hi;
  }

  // ---------------- one-sided Jacobi, n=32, register-resident, XOR
  // tournament, incremental norms (refreshed each sweep).
  {
    #pragma unroll 1
    for (int sweep = 0; sweep < 8; ++sweep) {
      // fresh own-norm (kills incremental drift)
      v2f s2n = {0.f, 0.f};
      #pragma unroll
      for (int i = 0; i < 8; ++i) s2n = fma2(v1[i], v1[i], s2n);
      float sn = s2n.x + s2n.y;
      sn += fshfl_xor(sn, 32);

      float offmax = 0.f;
      #pragma unroll 1
      for (int mask = 1; mask < 32; ++mask) {
        const int m = j ^ mask;
        v2f uu[8];
        #pragma unroll
        for (int i = 0; i < 8; ++i) {
          uu[i].x = fshfl_xor(v1[i].x, mask);
          uu[i].y = fshfl_xor(v1[i].y, mask);
        }
        float sb_o = fshfl_xor(sn, mask);    // partner's maintained norm
        v2f sgv = {0.f, 0.f};
        #pragma unroll
        for (int i = 0; i < 8; ++i) sgv = fma2(v1[i], uu[i], sgv);
        float sg = sgv.x + sgv.y;
        sg += fshfl_xor(sg, 32);
        const bool isp = j < m;
        float nA = isp ? sn : sb_o;
        float nB = isp ? sb_o : sn;
        float rel = sg * sg * frcp(fmaxf(nA * nB, 1e-30f));
        offmax = fmaxf(offmax, rel);
        if (rel > 1e-13f) {
          float uc = 0.5f * (nB - nA);
          float R  = fsqrt(uc * uc + sg * sg);
          float t  = sg * frcp(uc + ((uc >= 0.f) ? R : -R));
          float ct = frsq(1.f + t * t);
          float st = ct * t;
          float s  = isp ? -st : st;
          v2f ct2 = {ct, ct}, sv2 = {s, s};
          #pragma unroll
          for (int i = 0; i < 8; ++i)
            v1[i] = fma2(uu[i], sv2, v1[i] * ct2);
          // 2x2 Gram eigenvalue identity: a' = nA - t*sg, b' = nB + t*sg
          sn = fmaxf(isp ? (nA - t * sg) : (nB + t * sg), 0.f);
        }
      }
      #pragma unroll
      for (int mm = 1; mm <= 32; mm <<= 1) offmax = fmaxf(offmax, fshfl_xor(offmax, mm));
      if (offmax < 1e-11f) break;
    }
  }

  // ---------------- lambda_1 + ReEig + Ps = sqrt(clamp(lam1))*v1hat^T w2,
  // all from registers (fresh norm); Pt[16][PT_S] transposed (conflict-free).
  // t-loop unroll 2: caps outstanding w2 loads at 4 f32x4 (16 VGPRs) -- this
  // phase was the register-pressure spike that spilled under r12's cap-64.
  {
    v2f ssv = {0.f, 0.f};
    #pragma unroll
    for (int i = 0; i < 8; ++i) ssv = fma2(v1[i], v1[i], ssv);
    float ss = ssv.x + ssv.y;
    ss += fshfl_xor(ss, 32);
    float lam = fsqrt(ss);
    float sc1 = (lam > 0.f) ? (fsqrt(fmaxf(lam, 1e-4f)) * frcp(lam)) : 0.f;
    f32x4 acc0 = {0.f,0.f,0.f,0.f}, acc1 = acc0, acc2 = acc0, acc3 = acc0;
    #pragma unroll 2
    for (int t = 0; t < 8; ++t) {
      int rr = (h << 4) + 2 * t;
      const f32x4* wr0 = (const f32x4*)(w2g + rr * 16);
      const f32x4* wr1 = (const f32x4*)(w2g + (rr + 1) * 16);
      float vx = v1[t].x, vy = v1[t].y;
      f32x4 vx4 = {vx, vx, vx, vx};
      f32x4 vy4 = {vy, vy, vy, vy};
      acc0 = fma4(wr0[0], vx4, acc0); acc1 = fma4(wr0[1], vx4, acc1);
      acc2 = fma4(wr0[2], vx4, acc2); acc3 = fma4(wr0[3], vx4, acc3);
      acc0 = fma4(wr1[0], vy4, acc0); acc1 = fma4(wr1[1], vy4, acc1);
      acc2 = fma4(wr1[2], vy4, acc2); acc3 = fma4(wr1[3], vy4, acc3);
    }
    acc0.x = (acc0.x + fshfl_xor(acc0.x, 32)) * sc1;
    acc0.y = (acc0.y + fshfl_xor(acc0.y, 32)) * sc1;
    acc0.z = (acc0.z + fshfl_xor(acc0.z, 32)) * sc1;
    acc0.w = (acc0.w + fshfl_xor(acc0.w, 32)) * sc1;
    acc1.x = (acc1.x + fshfl_xor(acc1.x, 32)) * sc1;
    acc1.y = (acc1.y + fshfl_xor(acc1.y, 32)) * sc1;
    acc1.z = (acc1.z + fshfl_xor(acc1.z, 32)) * sc1;
    acc1.w = (acc1.w + fshfl_xor(acc1.w, 32)) * sc1;
    acc2.x = (acc2.x + fshfl_xor(acc2.x, 32)) * sc1;
    acc2.y = (acc2.y + fshfl_xor(acc2.y, 32)) * sc1;
    acc2.z = (acc2.z + fshfl_xor(acc2.z, 32)) * sc1;
    acc2.w = (acc2.w + fshfl_xor(acc2.w, 32)) * sc1;
    acc3.x = (acc3.x + fshfl_xor(acc3.x, 32)) * sc1;
    acc3.y = (acc3.y + fshfl_xor(acc3.y, 32)) * sc1;
    acc3.z = (acc3.z + fshfl_xor(acc3.z, 32)) * sc1;
    acc3.w = (acc3.w + fshfl_xor(acc3.w, 32)) * sc1;
    // lane (j,h) stores Ps[j][8h..8h+7]: h=0 -> acc0/acc1, h=1 -> acc2/acc3
    f32x4 lo = h ? acc2 : acc0;
    f32x4 hi = h ? acc3 : acc1;
    const int jb8 = h << 3;
    Pt[(jb8 + 0) * PT_S + j] = lo.x;
    Pt[(jb8 + 1) * PT_S + j] = lo.y;
    Pt[(jb8 + 2) * PT_S + j] = lo.z;
    Pt[(jb8 + 3) * PT_S + j] = lo.w;
    Pt[(jb8 + 4) * PT_S + j] = hi.x;
    Pt[(jb8 + 5) * PT_S + j] = hi.y;
    Pt[(jb8 + 6) * PT_S + j] = hi.z;
    Pt[(jb8 + 7) * PT_S + j] = hi.w;
  }
  FENCE();

  // ---------------- M2 = Ps^T Ps directly into stage-2 registers.
  // lane = c2 + 16*h4 owns rows 4h4..4h4+3 of M2 column c2.
  const int c2 = lane & 15;
  const int h4 = lane >> 4;
  f32x4 v2r;
  {
    v2f a0 = {0.f,0.f}, a1 = {0.f,0.f}, a2 = {0.f,0.f}, a3 = {0.f,0.f};
    #pragma unroll 2
    for (int kk = 0; kk < 32; kk += 4) {
      f32x4 aa = *(const f32x4*)(Pt + c2 * PT_S + kk);
      f32x4 b0 = *(const f32x4*)(Pt + (4 * h4 + 0) * PT_S + kk);
      f32x4 b1 = *(const f32x4*)(Pt + (4 * h4 + 1) * PT_S + kk);
      f32x4 b2 = *(const f32x4*)(Pt + (4 * h4 + 2) * PT_S + kk);
      f32x4 b3 = *(const f32x4*)(Pt + (4 * h4 + 3) * PT_S + kk);
      a0 = fma2(aa.lo, b0.lo, a0); a0 = fma2(aa.hi, b0.hi, a0);
      a1 = fma2(aa.lo, b1.lo, a1); a1 = fma2(aa.hi, b1.hi, a1);
      a2 = fma2(aa.lo, b2.lo, a2); a2 = fma2(aa.hi, b2.hi, a2);
      a3 = fma2(aa.lo, b3.lo, a3); a3 = fma2(aa.hi, b3.hi, a3);
    }
    v2r.x = a0.x + a0.y;
    v2r.y = a1.x + a1.y;
    v2r.z = a2.x + a2.y;
    v2r.w = a3.x + a3.y;
  }

  // ---------------- one-sided Jacobi, n=16, register-resident, XOR
  // tournament, incremental norms.
  {
    #pragma unroll 1
    for (int sweep = 0; sweep < 6; ++sweep) {
      v2f sp = fma2(v2r.hi, v2r.hi, v2r.lo * v2r.lo);
      float sn2 = sp.x + sp.y;
      sn2 += fshfl_xor(sn2, 16);
      sn2 += fshfl_xor(sn2, 32);
      float offmax = 0.f;
      #pragma unroll 1
      for (int mask = 1; mask < 16; ++mask) {
        const int m = c2 ^ mask;
        float u0 = fshfl_xor(v2r.x, mask);
        float u1 = fshfl_xor(v2r.y, mask);
        float u2 = fshfl_xor(v2r.z, mask);
        float u3 = fshfl_xor(v2r.w, mask);
        float sb_o = fshfl_xor(sn2, mask);
        v2f ua = {u0, u1}, ub = {u2, u3};
        v2f sgv = fma2(v2r.hi, ub, v2r.lo * ua);
        float sg = sgv.x + sgv.y;
        sg += fshfl_xor(sg, 16);
        sg += fshfl_xor(sg, 32);
        const bool isp = c2 < m;
        float nA = isp ? sn2 : sb_o;
        float nB = isp ? sb_o : sn2;
        float rel = sg * sg * frcp(fmaxf(nA * nB, 1e-30f));
        offmax = fmaxf(offmax, rel);
        if (rel > 1e-13f) {
          float uc = 0.5f * (nB - nA);
          float R  = fsqrt(uc * uc + sg * sg);
          float t  = sg * frcp(uc + ((uc >= 0.f) ? R : -R));
          float ct = frsq(1.f + t * t);
          float st = ct * t;
          float s  = isp ? -st : st;
          f32x4 ct4 = {ct, ct, ct, ct};
          f32x4 s4  = {s, s, s, s};
          f32x4 uu4 = {u0, u1, u2, u3};
          v2r = fma4(uu4, s4, v2r * ct4);
          sn2 = fmaxf(isp ? (nA - t * sg) : (nB + t * sg), 0.f);
        }
      }
      #pragma unroll
      for (int mm = 1; mm <= 32; mm <<= 1) offmax = fmaxf(offmax, fshfl_xor(offmax, mm));
      if (offmax < 1e-11f) break;
    }
  }

  // ---------------- Qb row c2 = (V2^T w3)[c2][:] * sqrt(clamp(lam2)) from regs
  {
    f32x4 qq = {0.f, 0.f, 0.f, 0.f};
    f32x4 w0 = *(const f32x4*)(w3g + (4 * h4 + 0) * 4);
    f32x4 w1r = *(const f32x4*)(w3g + (4 * h4 + 1) * 4);
    f32x4 w2r = *(const f32x4*)(w3g + (4 * h4 + 2) * 4);
    f32x4 w3r = *(const f32x4*)(w3g + (4 * h4 + 3) * 4);
    f32x4 vv0 = {v2r.x, v2r.x, v2r.x, v2r.x};
    f32x4 vv1 = {v2r.y, v2r.y, v2r.y, v2r.y};
    f32x4 vv2 = {v2r.z, v2r.z, v2r.z, v2r.z};
    f32x4 vv3 = {v2r.w, v2r.w, v2r.w, v2r.w};
    qq = fma4(w0, vv0, qq); qq = fma4(w1r, vv1, qq);
    qq = fma4(w2r, vv2, qq); qq = fma4(w3r, vv3, qq);
    v2f sp = fma2(v2r.hi, v2r.hi, v2r.lo * v2r.lo);
    float ssp = sp.x + sp.y;
    float q0 = qq.x, q1 = qq.y, q2 = qq.z, q3 = qq.w;
    q0 += fshfl_xor(q0, 16); q0 += fshfl_xor(q0, 32);
    q1 += fshfl_xor(q1, 16); q1 += fshfl_xor(q1, 32);
    q2 += fshfl_xor(q2, 16); q2 += fshfl_xor(q2, 32);
    q3 += fshfl_xor(q3, 16); q3 += fshfl_xor(q3, 32);
    ssp += fshfl_xor(ssp, 16); ssp += fshfl_xor(ssp, 32);
    float lam = fsqrt(ssp);
    float scl = (lam > 0.f) ? (frcp(lam) * fsqrt(fmaxf(lam, 1e-4f))) : 0.f;
    if (h4 == 0)
      *(f32x4*)(Cc + c2 * 4) = (f32x4){q0 * scl, q1 * scl, q2 * scl, q3 * scl};
  }
  FENCE();

  // ---------------- stage 3: one-sided Jacobi ON THE 16x4 FACTOR, with
  // accumulated rotations J (eigenvectors of M3 = Q^T Q). 5 sweeps.
  float qv = Cc[lane];            // Qb[kq][jq], kq*4+jq == lane
  const int kq = lane >> 2;
  const int jq = lane & 3;
  float jv = (kq == jq) ? 1.f : 0.f;
  {
    #define ROT3(P_, Q_) do {                                             \
      float w_ = fshfl_xor(qv, (P_) ^ (Q_));                              \
      float s1 = qv * qv, s2 = w_ * w_, s3 = qv * w_;                     \
      s1 += fshfl_xor(s1, 4);  s2 += fshfl_xor(s2, 4);  s3 += fshfl_xor(s3, 4);  \
      s1 += fshfl_xor(s1, 8);  s2 += fshfl_xor(s2, 8);  s3 += fshfl_xor(s3, 8);  \
      s1 += fshfl_xor(s1, 16); s2 += fshfl_xor(s2, 16); s3 += fshfl_xor(s3, 16); \
      s1 += fshfl_xor(s1, 32); s2 += fshfl_xor(s2, 32); s3 += fshfl_xor(s3, 32); \
      bool isp = (jq == (P_)), isq = (jq == (Q_));                        \
      float sa = isp ? s1 : s2;                                           \
      float sb = isp ? s2 : s1;                                           \
      float u_ = 0.5f * (sb - sa);                                        \
      float R_ = fsqrt(u_ * u_ + s3 * s3);                                \
      float dn_ = u_ + copysignf(fmaxf(R_, 1e-30f), u_);                  \
      float t_ = s3 * frcp(dn_);                                          \
      float ct = frsq(1.f + t_ * t_);                                     \
      float st = ct * t_;                                                 \
      float wj_ = fshfl_xor(jv, (P_) ^ (Q_));                             \
      float nv  = isp ? (ct * qv - st * w_)  : (st * w_  + ct * qv);      \
      float nvj = isp ? (ct * jv - st * wj_) : (st * wj_ + ct * jv);      \
      if (isp | isq) { qv = nv; jv = nvj; }                               \
    } while (0)

    #pragma unroll 1
    for (int sweep = 0; sweep < 5; ++sweep) {
      ROT3(0,1); ROT3(2,3); ROT3(0,2); ROT3(1,3); ROT3(0,3); ROT3(1,2);
    }
    #undef ROT3
  }

  // ---------------- lambda_3 = ||col||^2, LogEig via J, FC, log_softmax
  {
    float ss = qv * qv;
    ss += fshfl_xor(ss, 4); ss += fshfl_xor(ss, 8);
    ss += fshfl_xor(ss, 16); ss += fshfl_xor(ss, 32);
    float lwv = logf(fmaxf(ss, 1e-10f));       // log eigenvalue of column jq
    if (kq < 4)  Cc[64 + kq * 4 + jq] = jv;    // J, row-major 4x4
    if (kq == 0) Cc[80 + jq] = lwv;            // lanes 0..3: per-column loglam
    FENCE();

    float f = 0.f;
    if (lane < 16) {
      int i3 = lane >> 2, j3 = lane & 3;
      #pragma unroll
      for (int c = 0; c < 4; ++c)
        f += Cc[80 + c] * Cc[64 + i3 * 4 + c] * Cc[64 + j3 * 4 + c];
    }
    float t0 = 0.f, t1 = 0.f;
    if (lane < 16) { t0 = f * fcg[2 * lane]; t1 = f * fcg[2 * lane + 1]; }
    t0 += fshfl_xor(t0, 1); t1 += fshfl_xor(t1, 1);
    t0 += fshfl_xor(t0, 2); t1 += fshfl_xor(t1, 2);
    t0 += fshfl_xor(t0, 4); t1 += fshfl_xor(t1, 4);
    t0 += fshfl_xor(t0, 8); t1 += fshfl_xor(t1, 8);
    float mx  = fmaxf(t0, t1);
    float lse = mx + logf(expf(t0 - mx) + expf(t1 - mx));

    float* outFeat = outg + (size_t)B * 2;
    if (lane < 16) outFeat[(size_t)b * 16 + lane] = f;
    if (lane < 2)  outg[(size_t)b * 2 + lane] = (lane == 0 ? t0 : t1) - lse;
  }
}

extern "C" void kernel_launch(void* const* d_in, const int* in_sizes, int n_in,
                              void* d_out, int out_size, void* d_ws, size_t ws_size,
                              hipStream_t stream) {
  const float* x  = (const float*)d_in[0];
  const float* w1 = (const float*)d_in[1];
  const float* w2 = (const float*)d_in[2];
  const float* w3 = (const float*)d_in[3];
  const float* fc = (const float*)d_in[4];
  float* out = (float*)d_out;
  int B = in_sizes[0] / 1024;
  int grid = (B + 3) / 4;
  hipLaunchKernelGGL(spd_fused, dim3(grid), dim3(256), 0, stream,
                     x, w1, w2, w3, fc, out, B);
}

// Round 14
// 2058.376 us; speedup vs baseline: 1.0977x; 1.0018x over previous
//
#include <hip/hip_runtime.h>

// Wave-level LDS ordering fence for the few remaining LDS phase transitions.
#define FENCE() asm volatile("s_waitcnt lgkmcnt(0)" ::: "memory")

typedef float v2f   __attribute__((ext_vector_type(2)));
typedef float f32x4 __attribute__((ext_vector_type(4)));

__device__ __forceinline__ float fshfl_xor(float v, int m) { return __shfl_xor(v, m, 64); }
__device__ __forceinline__ float fsqrt(float x) { return __builtin_amdgcn_sqrtf(x); }
__device__ __forceinline__ float frcp (float x) { return __builtin_amdgcn_rcpf(x); }
__device__ __forceinline__ float frsq (float x) { return __builtin_amdgcn_rsqf(x); }
__device__ __forceinline__ v2f   fma2(v2f a, v2f b, v2f c)       { return __builtin_elementwise_fma(a, b, c); }
__device__ __forceinline__ f32x4 fma4(f32x4 a, f32x4 b, f32x4 c) { return __builtin_elementwise_fma(a, b, c); }

// One block = 256 threads = 4 waves, one 32x32 SPD matrix per wave.
// r14 = r13 minus ONE bug: r13's "#pragma unroll 2" on the Ps t-loop made t
// a runtime index into the v1[] register array -> SROA demoted v1 to scratch
// (rule #20; WRITE_SIZE 305MB). Back to full unroll: every v1[t] subscript
// is compile-time. launch_bounds(256,6) kept: VGPR budget ~84 >= natural
// usage ~60-70 (clean at budget-128 in r11), occupancy cap 75%.
// Spill tripwire: WRITE_SIZE must read ~2.3MB.
// LDS: 4*1152*4 = 18432 B/block.
#define PT_S 34
__global__ __launch_bounds__(256, 6) void spd_fused(
    const float* __restrict__ xg,
    const float* __restrict__ w1g,
    const float* __restrict__ w2g,
    const float* __restrict__ w3g,
    const float* __restrict__ fcg,
    float* __restrict__ outg,
    int B)
{
  __shared__ float slot[4][1152];

  const int tid  = threadIdx.x;
  const int wid  = tid >> 6;
  const int lane = tid & 63;

  float* Cc = slot[wid];          // x (stride 32) -> M1 cols (stride 36) -> Qb/J scratch
  float* Pt = slot[wid] + 576;    // Ps transposed [16][PT_S], in dead M1 space

  const long b = (long)blockIdx.x * 4 + wid;
  if (b >= B) return;

  // ---------------- load x -> Cc row-major [32][32] (stride 32)
  {
    const f32x4* xv = (const f32x4*)(xg + (size_t)b * 1024);
    f32x4* c4 = (f32x4*)Cc;
    #pragma unroll
    for (int jj = 0; jj < 4; ++jj) {
      int i4 = lane + 64 * jj;
      c4[i4] = xv[i4];
    }
  }
  FENCE();

  const int j = lane & 31;
  const int h = lane >> 5;

  // ---------------- Tmat = x * w1 in registers (packed). T2[e] = rows
  // {16h+2e, +1} of column j. Uses x symmetry: read x rows as f32x4.
  // (c-loop unroll 4 is safe: T2 subscripts are literal constants.)
  v2f T2[8];
  {
    #pragma unroll
    for (int e = 0; e < 8; ++e) T2[e] = (v2f){0.f, 0.f};
    const f32x4* c4 = (const f32x4*)Cc;
    #pragma unroll 4
    for (int c = 0; c < 32; ++c) {
      float wv = w1g[c * 32 + j];
      v2f wv2 = {wv, wv};
      f32x4 x0 = c4[c * 8 + h * 4 + 0];
      f32x4 x1 = c4[c * 8 + h * 4 + 1];
      f32x4 x2 = c4[c * 8 + h * 4 + 2];
      f32x4 x3 = c4[c * 8 + h * 4 + 3];
      T2[0] = fma2(x0.lo, wv2, T2[0]); T2[1] = fma2(x0.hi, wv2, T2[1]);
      T2[2] = fma2(x1.lo, wv2, T2[2]); T2[3] = fma2(x1.hi, wv2, T2[3]);
      T2[4] = fma2(x2.lo, wv2, T2[4]); T2[5] = fma2(x2.hi, wv2, T2[5]);
      T2[6] = fma2(x3.lo, wv2, T2[6]); T2[7] = fma2(x3.hi, wv2, T2[7]);
    }
  }
  FENCE();   // all x reads complete before M1 overwrites Cc

  // ---------------- M1 = w1^T * Tmat -> Cc linear column-major, stride 36.
  // (e-loop FULL unroll: T2[e>>1][e&1] must stay compile-time.)
  {
    const f32x4* w14 = (const f32x4*)w1g;   // row r = w14[r*8 + 0..7]
    #pragma unroll
    for (int ih2 = 0; ih2 < 4; ++ih2) {     // output rows 8*ih2 .. 8*ih2+7
      f32x4 A = {0.f, 0.f, 0.f, 0.f};
      f32x4 Bv = {0.f, 0.f, 0.f, 0.f};
      #pragma unroll
      for (int e = 0; e < 16; ++e) {
        int r = 16 * h + e;
        float tv = T2[e >> 1][e & 1];
        f32x4 tv4 = {tv, tv, tv, tv};
        A  = fma4(w14[r * 8 + ih2 * 2],     tv4, A);
        Bv = fma4(w14[r * 8 + ih2 * 2 + 1], tv4, Bv);
      }
      A.x += fshfl_xor(A.x, 32);  A.y += fshfl_xor(A.y, 32);
      A.z += fshfl_xor(A.z, 32);  A.w += fshfl_xor(A.w, 32);
      Bv.x += fshfl_xor(Bv.x, 32); Bv.y += fshfl_xor(Bv.y, 32);
      Bv.z += fshfl_xor(Bv.z, 32); Bv.w += fshfl_xor(Bv.w, 32);
      if (h == (ih2 & 1)) {
        *(f32x4*)(Cc + j * 36 + ih2 * 8)     = A;
        *(f32x4*)(Cc + j * 36 + ih2 * 8 + 4) = Bv;
      }
    }
  }
  FENCE();

  // ---------------- load own column half into v2f registers (one-time)
  v2f v1[8];
  {
    const float* bp = Cc + j * 36 + (h << 4);
    f32x4 q0 = *(const f32x4*)(bp);
    f32x4 q1 = *(const f32x4*)(bp + 4);
    f32x4 q2 = *(const f32x4*)(bp + 8);
    f32x4 q3 = *(const f32x4*)(bp + 12);
    v1[0] = q0.lo; v1[1] = q0.hi; v1[2] = q1.lo; v1[3] = q1.hi;
    v1[4] = q2.lo; v1[5] = q2.hi; v1[6] = q3.lo; v1[7] = q3.hi;
  }

  // ---------------- one-sided Jacobi, n=32, register-resident, XOR
  // tournament, incremental norms (refreshed each sweep).
  {
    #pragma unroll 1
    for (int sweep = 0; sweep < 8; ++sweep) {
      // fresh own-norm (kills incremental drift)
      v2f s2n = {0.f, 0.f};
      #pragma unroll
      for (int i = 0; i < 8; ++i) s2n = fma2(v1[i], v1[i], s2n);
      float sn = s2n.x + s2n.y;
      sn += fshfl_xor(sn, 32);

      float offmax = 0.f;
      #pragma unroll 1
      for (int mask = 1; mask < 32; ++mask) {
        const int m = j ^ mask;
        v2f uu[8];
        #pragma unroll
        for (int i = 0; i < 8; ++i) {
          uu[i].x = fshfl_xor(v1[i].x, mask);
          uu[i].y = fshfl_xor(v1[i].y, mask);
        }
        float sb_o = fshfl_xor(sn, mask);    // partner's maintained norm
        v2f sgv = {0.f, 0.f};
        #pragma unroll
        for (int i = 0; i < 8; ++i) sgv = fma2(v1[i], uu[i], sgv);
        float sg = sgv.x + sgv.y;
        sg += fshfl_xor(sg, 32);
        const bool isp = j < m;
        float nA = isp ? sn : sb_o;
        float nB = isp ? sb_o : sn;
        float rel = sg * sg * frcp(fmaxf(nA * nB, 1e-30f));
        offmax = fmaxf(offmax, rel);
        if (rel > 1e-13f) {
          float uc = 0.5f * (nB - nA);
          float R  = fsqrt(uc * uc + sg * sg);
          float t  = sg * frcp(uc + ((uc >= 0.f) ? R : -R));
          float ct = frsq(1.f + t * t);
          float st = ct * t;
          float s  = isp ? -st : st;
          v2f ct2 = {ct, ct}, sv2 = {s, s};
          #pragma unroll
          for (int i = 0; i < 8; ++i)
            v1[i] = fma2(uu[i], sv2, v1[i] * ct2);
          // 2x2 Gram eigenvalue identity: a' = nA - t*sg, b' = nB + t*sg
          sn = fmaxf(isp ? (nA - t * sg) : (nB + t * sg), 0.f);
        }
      }
      #pragma unroll
      for (int mm = 1; mm <= 32; mm <<= 1) offmax = fmaxf(offmax, fshfl_xor(offmax, mm));
      if (offmax < 1e-11f) break;
    }
  }

  // ---------------- lambda_1 + ReEig + Ps = sqrt(clamp(lam1))*v1hat^T w2,
  // all from registers (fresh norm); Pt[16][PT_S] transposed (conflict-free).
  // t-loop FULL unroll: v1[t] must be compile-time-indexed (r13's unroll-2
  // made t runtime -> v1 to scratch -> 305MB spill).
  {
    v2f ssv = {0.f, 0.f};
    #pragma unroll
    for (int i = 0; i < 8; ++i) ssv = fma2(v1[i], v1[i], ssv);
    float ss = ssv.x + ssv.y;
    ss += fshfl_xor(ss, 32);
    float lam = fsqrt(ss);
    float sc1 = (lam > 0.f) ? (fsqrt(fmaxf(lam, 1e-4f)) * frcp(lam)) : 0.f;
    f32x4 acc0 = {0.f,0.f,0.f,0.f}, acc1 = acc0, acc2 = acc0, acc3 = acc0;
    #pragma unroll
    for (int t = 0; t < 8; ++t) {
      int rr = (h << 4) + 2 * t;
      const f32x4* wr0 = (const f32x4*)(w2g + rr * 16);
      const f32x4* wr1 = (const f32x4*)(w2g + (rr + 1) * 16);
      float vx = v1[t].x, vy = v1[t].y;
      f32x4 vx4 = {vx, vx, vx, vx};
      f32x4 vy4 = {vy, vy, vy, vy};
      acc0 = fma4(wr0[0], vx4, acc0); acc1 = fma4(wr0[1], vx4, acc1);
      acc2 = fma4(wr0[2], vx4, acc2); acc3 = fma4(wr0[3], vx4, acc3);
      acc0 = fma4(wr1[0], vy4, acc0); acc1 = fma4(wr1[1], vy4, acc1);
      acc2 = fma4(wr1[2], vy4, acc2); acc3 = fma4(wr1[3], vy4, acc3);
    }
    acc0.x = (acc0.x + fshfl_xor(acc0.x, 32)) * sc1;
    acc0.y = (acc0.y + fshfl_xor(acc0.y, 32)) * sc1;
    acc0.z = (acc0.z + fshfl_xor(acc0.z, 32)) * sc1;
    acc0.w = (acc0.w + fshfl_xor(acc0.w, 32)) * sc1;
    acc1.x = (acc1.x + fshfl_xor(acc1.x, 32)) * sc1;
    acc1.y = (acc1.y + fshfl_xor(acc1.y, 32)) * sc1;
    acc1.z = (acc1.z + fshfl_xor(acc1.z, 32)) * sc1;
    acc1.w = (acc1.w + fshfl_xor(acc1.w, 32)) * sc1;
    acc2.x = (acc2.x + fshfl_xor(acc2.x, 32)) * sc1;
    acc2.y = (acc2.y + fshfl_xor(acc2.y, 32)) * sc1;
    acc2.z = (acc2.z + fshfl_xor(acc2.z, 32)) * sc1;
    acc2.w = (acc2.w + fshfl_xor(acc2.w, 32)) * sc1;
    acc3.x = (acc3.x + fshfl_xor(acc3.x, 32)) * sc1;
    acc3.y = (acc3.y + fshfl_xor(acc3.y, 32)) * sc1;
    acc3.z = (acc3.z + fshfl_xor(acc3.z, 32)) * sc1;
    acc3.w = (acc3.w + fshfl_xor(acc3.w, 32)) * sc1;
    // lane (j,h) stores Ps[j][8h..8h+7]: h=0 -> acc0/acc1, h=1 -> acc2/acc3
    f32x4 lo = h ? acc2 : acc0;
    f32x4 hi = h ? acc3 : acc1;
    const int jb8 = h << 3;
    Pt[(jb8 + 0) * PT_S + j] = lo.x;
    Pt[(jb8 + 1) * PT_S + j] = lo.y;
    Pt[(jb8 + 2) * PT_S + j] = lo.z;
    Pt[(jb8 + 3) * PT_S + j] = lo.w;
    Pt[(jb8 + 4) * PT_S + j] = hi.x;
    Pt[(jb8 + 5) * PT_S + j] = hi.y;
    Pt[(jb8 + 6) * PT_S + j] = hi.z;
    Pt[(jb8 + 7) * PT_S + j] = hi.w;
  }
  FENCE();

  // ---------------- M2 = Ps^T Ps directly into stage-2 registers.
  // lane = c2 + 16*h4 owns rows 4h4..4h4+3 of M2 column c2.
  // (kk-loop unroll 2 safe: only LDS pointers use kk.)
  const int c2 = lane & 15;
  const int h4 = lane >> 4;
  f32x4 v2r;
  {
    v2f a0 = {0.f,0.f}, a1 = {0.f,0.f}, a2 = {0.f,0.f}, a3 = {0.f,0.f};
    #pragma unroll 2
    for (int kk = 0; kk < 32; kk += 4) {
      f32x4 aa = *(const f32x4*)(Pt + c2 * PT_S + kk);
      f32x4 b0 = *(const f32x4*)(Pt + (4 * h4 + 0) * PT_S + kk);
      f32x4 b1 = *(const f32x4*)(Pt + (4 * h4 + 1) * PT_S + kk);
      f32x4 b2 = *(const f32x4*)(Pt + (4 * h4 + 2) * PT_S + kk);
      f32x4 b3 = *(const f32x4*)(Pt + (4 * h4 + 3) * PT_S + kk);
      a0 = fma2(aa.lo, b0.lo, a0); a0 = fma2(aa.hi, b0.hi, a0);
      a1 = fma2(aa.lo, b1.lo, a1); a1 = fma2(aa.hi, b1.hi, a1);
      a2 = fma2(aa.lo, b2.lo, a2); a2 = fma2(aa.hi, b2.hi, a2);
      a3 = fma2(aa.lo, b3.lo, a3); a3 = fma2(aa.hi, b3.hi, a3);
    }
    v2r.x = a0.x + a0.y;
    v2r.y = a1.x + a1.y;
    v2r.z = a2.x + a2.y;
    v2r.w = a3.x + a3.y;
  }

  // ---------------- one-sided Jacobi, n=16, register-resident, XOR
  // tournament, incremental norms.
  {
    #pragma unroll 1
    for (int sweep = 0; sweep < 6; ++sweep) {
      v2f sp = fma2(v2r.hi, v2r.hi, v2r.lo * v2r.lo);
      float sn2 = sp.x + sp.y;
      sn2 += fshfl_xor(sn2, 16);
      sn2 += fshfl_xor(sn2, 32);
      float offmax = 0.f;
      #pragma unroll 1
      for (int mask = 1; mask < 16; ++mask) {
        const int m = c2 ^ mask;
        float u0 = fshfl_xor(v2r.x, mask);
        float u1 = fshfl_xor(v2r.y, mask);
        float u2 = fshfl_xor(v2r.z, mask);
        float u3 = fshfl_xor(v2r.w, mask);
        float sb_o = fshfl_xor(sn2, mask);
        v2f ua = {u0, u1}, ub = {u2, u3};
        v2f sgv = fma2(v2r.hi, ub, v2r.lo * ua);
        float sg = sgv.x + sgv.y;
        sg += fshfl_xor(sg, 16);
        sg += fshfl_xor(sg, 32);
        const bool isp = c2 < m;
        float nA = isp ? sn2 : sb_o;
        float nB = isp ? sb_o : sn2;
        float rel = sg * sg * frcp(fmaxf(nA * nB, 1e-30f));
        offmax = fmaxf(offmax, rel);
        if (rel > 1e-13f) {
          float uc = 0.5f * (nB - nA);
          float R  = fsqrt(uc * uc + sg * sg);
          float t  = sg * frcp(uc + ((uc >= 0.f) ? R : -R));
          float ct = frsq(1.f + t * t);
          float st = ct * t;
          float s  = isp ? -st : st;
          f32x4 ct4 = {ct, ct, ct, ct};
          f32x4 s4  = {s, s, s, s};
          f32x4 uu4 = {u0, u1, u2, u3};
          v2r = fma4(uu4, s4, v2r * ct4);
          sn2 = fmaxf(isp ? (nA - t * sg) : (nB + t * sg), 0.f);
        }
      }
      #pragma unroll
      for (int mm = 1; mm <= 32; mm <<= 1) offmax = fmaxf(offmax, fshfl_xor(offmax, mm));
      if (offmax < 1e-11f) break;
    }
  }

  // ---------------- Qb row c2 = (V2^T w3)[c2][:] * sqrt(clamp(lam2)) from regs
  {
    f32x4 qq = {0.f, 0.f, 0.f, 0.f};
    f32x4 w0 = *(const f32x4*)(w3g + (4 * h4 + 0) * 4);
    f32x4 w1r = *(const f32x4*)(w3g + (4 * h4 + 1) * 4);
    f32x4 w2r = *(const f32x4*)(w3g + (4 * h4 + 2) * 4);
    f32x4 w3r = *(const f32x4*)(w3g + (4 * h4 + 3) * 4);
    f32x4 vv0 = {v2r.x, v2r.x, v2r.x, v2r.x};
    f32x4 vv1 = {v2r.y, v2r.y, v2r.y, v2r.y};
    f32x4 vv2 = {v2r.z, v2r.z, v2r.z, v2r.z};
    f32x4 vv3 = {v2r.w, v2r.w, v2r.w, v2r.w};
    qq = fma4(w0, vv0, qq); qq = fma4(w1r, vv1, qq);
    qq = fma4(w2r, vv2, qq); qq = fma4(w3r, vv3, qq);
    v2f sp = fma2(v2r.hi, v2r.hi, v2r.lo * v2r.lo);
    float ssp = sp.x + sp.y;
    float q0 = qq.x, q1 = qq.y, q2 = qq.z, q3 = qq.w;
    q0 += fshfl_xor(q0, 16); q0 += fshfl_xor(q0, 32);
    q1 += fshfl_xor(q1, 16); q1 += fshfl_xor(q1, 32);
    q2 += fshfl_xor(q2, 16); q2 += fshfl_xor(q2, 32);
    q3 += fshfl_xor(q3, 16); q3 += fshfl_xor(q3, 32);
    ssp += fshfl_xor(ssp, 16); ssp += fshfl_xor(ssp, 32);
    float lam = fsqrt(ssp);
    float scl = (lam > 0.f) ? (frcp(lam) * fsqrt(fmaxf(lam, 1e-4f))) : 0.f;
    if (h4 == 0)
      *(f32x4*)(Cc + c2 * 4) = (f32x4){q0 * scl, q1 * scl, q2 * scl, q3 * scl};
  }
  FENCE();

  // ---------------- stage 3: one-sided Jacobi ON THE 16x4 FACTOR, with
  // accumulated rotations J (eigenvectors of M3 = Q^T Q). 5 sweeps.
  float qv = Cc[lane];            // Qb[kq][jq], kq*4+jq == lane
  const int kq = lane >> 2;
  const int jq = lane & 3;
  float jv = (kq == jq) ? 1.f : 0.f;
  {
    #define ROT3(P_, Q_) do {                                             \
      float w_ = fshfl_xor(qv, (P_) ^ (Q_));                              \
      float s1 = qv * qv, s2 = w_ * w_, s3 = qv * w_;                     \
      s1 += fshfl_xor(s1, 4);  s2 += fshfl_xor(s2, 4);  s3 += fshfl_xor(s3, 4);  \
      s1 += fshfl_xor(s1, 8);  s2 += fshfl_xor(s2, 8);  s3 += fshfl_xor(s3, 8);  \
      s1 += fshfl_xor(s1, 16); s2 += fshfl_xor(s2, 16); s3 += fshfl_xor(s3, 16); \
      s1 += fshfl_xor(s1, 32); s2 += fshfl_xor(s2, 32); s3 += fshfl_xor(s3, 32); \
      bool isp = (jq == (P_)), isq = (jq == (Q_));                        \
      float sa = isp ? s1 : s2;                                           \
      float sb = isp ? s2 : s1;                                           \
      float u_ = 0.5f * (sb - sa);                                        \
      float R_ = fsqrt(u_ * u_ + s3 * s3);                                \
      float dn_ = u_ + copysignf(fmaxf(R_, 1e-30f), u_);                  \
      float t_ = s3 * frcp(dn_);                                          \
      float ct = frsq(1.f + t_ * t_);                                     \
      float st = ct * t_;                                                 \
      float wj_ = fshfl_xor(jv, (P_) ^ (Q_));                             \
      float nv  = isp ? (ct * qv - st * w_)  : (st * w_  + ct * qv);      \
      float nvj = isp ? (ct * jv - st * wj_) : (st * wj_ + ct * jv);      \
      if (isp | isq) { qv = nv; jv = nvj; }                               \
    } while (0)

    #pragma unroll 1
    for (int sweep = 0; sweep < 5; ++sweep) {
      ROT3(0,1); ROT3(2,3); ROT3(0,2); ROT3(1,3); ROT3(0,3); ROT3(1,2);
    }
    #undef ROT3
  }

  // ---------------- lambda_3 = ||col||^2, LogEig via J, FC, log_softmax
  {
    float ss = qv * qv;
    ss += fshfl_xor(ss, 4); ss += fshfl_xor(ss, 8);
    ss += fshfl_xor(ss, 16); ss += fshfl_xor(ss, 32);
    float lwv = logf(fmaxf(ss, 1e-10f));       // log eigenvalue of column jq
    if (kq < 4)  Cc[64 + kq * 4 + jq] = jv;    // J, row-major 4x4
    if (kq == 0) Cc[80 + jq] = lwv;            // lanes 0..3: per-column loglam
    FENCE();

    float f = 0.f;
    if (lane < 16) {
      int i3 = lane >> 2, j3 = lane & 3;
      #pragma unroll
      for (int c = 0; c < 4; ++c)
        f += Cc[80 + c] * Cc[64 + i3 * 4 + c] * Cc[64 + j3 * 4 + c];
    }
    float t0 = 0.f, t1 = 0.f;
    if (lane < 16) { t0 = f * fcg[2 * lane]; t1 = f * fcg[2 * lane + 1]; }
    t0 += fshfl_xor(t0, 1); t1 += fshfl_xor(t1, 1);
    t0 += fshfl_xor(t0, 2); t1 += fshfl_xor(t1, 2);
    t0 += fshfl_xor(t0, 4); t1 += fshfl_xor(t1, 4);
    t0 += fshfl_xor(t0, 8); t1 += fshfl_xor(t1, 8);
    float mx  = fmaxf(t0, t1);
    float lse = mx + logf(expf(t0 - mx) + expf(t1 - mx));

    float* outFeat = outg + (size_t)B * 2;
    if (lane < 16) outFeat[(size_t)b * 16 + lane] = f;
    if (lane < 2)  outg[(size_t)b * 2 + lane] = (lane == 0 ? t0 : t1) - lse;
  }
}

extern "C" void kernel_launch(void* const* d_in, const int* in_sizes, int n_in,
                              void* d_out, int out_size, void* d_ws, size_t ws_size,
                              hipStream_t stream) {
  const float* x  = (const float*)d_in[0];
  const float* w1 = (const float*)d_in[1];
  const float* w2 = (const float*)d_in[2];
  const float* w3 = (const float*)d_in[3];
  const float* fc = (const float*)d_in[4];
  float* out = (float*)d_out;
  int B = in_sizes[0] / 1024;
  int grid = (B + 3) / 4;
  hipLaunchKernelGGL(spd_fused, dim3(grid), dim3(256), 0, stream,
                     x, w1, w2, w3, fc, out, B);
}

// Round 15
// 2030.034 us; speedup vs baseline: 1.1130x; 1.0140x over previous
//
#include <hip/hip_runtime.h>

// Wave-level LDS ordering fence for the few remaining LDS phase transitions.
#define FENCE() asm volatile("s_waitcnt lgkmcnt(0)" ::: "memory")

typedef float v2f   __attribute__((ext_vector_type(2)));
typedef float f32x4 __attribute__((ext_vector_type(4)));

__device__ __forceinline__ float fshfl_xor(float v, int m) { return __shfl_xor(v, m, 64); }
__device__ __forceinline__ float fsqrt(float x) { return __builtin_amdgcn_sqrtf(x); }
__device__ __forceinline__ float frcp (float x) { return __builtin_amdgcn_rcpf(x); }
__device__ __forceinline__ float frsq (float x) { return __builtin_amdgcn_rsqf(x); }
__device__ __forceinline__ v2f   fma2(v2f a, v2f b, v2f c)       { return __builtin_elementwise_fma(a, b, c); }
__device__ __forceinline__ f32x4 fma4(f32x4 a, f32x4 b, f32x4 c) { return __builtin_elementwise_fma(a, b, c); }

// One block = 256 threads = 4 waves, one 32x32 SPD matrix per wave.
// r15 vs r14: r14 proved the spill is pure budget pressure (removing r13's
// unroll-2 changed nothing; peak demand in (80,128], over the bounds-6
// budget ~80). Measured quadrants: clean+46%occ=2259us (r11, bounds4),
// spill+87%=2078 (r12, bounds8), spill+67%=2058 (r14, bounds6). This round
// targets the unexplored clean+high-occ quadrant:
//  - NO waves-per-EU arg: no explicit budget -> no panic spill; no metadata
//    occupancy cap (measured: arg tracks occupancy 8->87%,6->67%,4->46%);
//    HW occupancy then follows actual VGPR use.
//  - sched_barrier(0) mid-Ps-phase: splits the 16 hoisted w2 f32x4 loads
//    (64 VGPRs in flight -- the demand spike) into 2x8, nudging natural
//    usage toward <=64 (8 waves/SIMD).
// Spill tripwire: WRITE_SIZE must read ~2.3MB.
// LDS: 4*1152*4 = 18432 B/block.
#define PT_S 34
__global__ __launch_bounds__(256) void spd_fused(
    const float* __restrict__ xg,
    const float* __restrict__ w1g,
    const float* __restrict__ w2g,
    const float* __restrict__ w3g,
    const float* __restrict__ fcg,
    float* __restrict__ outg,
    int B)
{
  __shared__ float slot[4][1152];

  const int tid  = threadIdx.x;
  const int wid  = tid >> 6;
  const int lane = tid & 63;

  float* Cc = slot[wid];          // x (stride 32) -> M1 cols (stride 36) -> Qb/J scratch
  float* Pt = slot[wid] + 576;    // Ps transposed [16][PT_S], in dead M1 space

  const long b = (long)blockIdx.x * 4 + wid;
  if (b >= B) return;

  // ---------------- load x -> Cc row-major [32][32] (stride 32)
  {
    const f32x4* xv = (const f32x4*)(xg + (size_t)b * 1024);
    f32x4* c4 = (f32x4*)Cc;
    #pragma unroll
    for (int jj = 0; jj < 4; ++jj) {
      int i4 = lane + 64 * jj;
      c4[i4] = xv[i4];
    }
  }
  FENCE();

  const int j = lane & 31;
  const int h = lane >> 5;

  // ---------------- Tmat = x * w1 in registers (packed). T2[e] = rows
  // {16h+2e, +1} of column j. Uses x symmetry: read x rows as f32x4.
  // (c-loop unroll 4 is safe: T2 subscripts are literal constants.)
  v2f T2[8];
  {
    #pragma unroll
    for (int e = 0; e < 8; ++e) T2[e] = (v2f){0.f, 0.f};
    const f32x4* c4 = (const f32x4*)Cc;
    #pragma unroll 4
    for (int c = 0; c < 32; ++c) {
      float wv = w1g[c * 32 + j];
      v2f wv2 = {wv, wv};
      f32x4 x0 = c4[c * 8 + h * 4 + 0];
      f32x4 x1 = c4[c * 8 + h * 4 + 1];
      f32x4 x2 = c4[c * 8 + h * 4 + 2];
      f32x4 x3 = c4[c * 8 + h * 4 + 3];
      T2[0] = fma2(x0.lo, wv2, T2[0]); T2[1] = fma2(x0.hi, wv2, T2[1]);
      T2[2] = fma2(x1.lo, wv2, T2[2]); T2[3] = fma2(x1.hi, wv2, T2[3]);
      T2[4] = fma2(x2.lo, wv2, T2[4]); T2[5] = fma2(x2.hi, wv2, T2[5]);
      T2[6] = fma2(x3.lo, wv2, T2[6]); T2[7] = fma2(x3.hi, wv2, T2[7]);
    }
  }
  FENCE();   // all x reads complete before M1 overwrites Cc

  // ---------------- M1 = w1^T * Tmat -> Cc linear column-major, stride 36.
  // (e-loop FULL unroll: T2[e>>1][e&1] must stay compile-time.)
  {
    const f32x4* w14 = (const f32x4*)w1g;   // row r = w14[r*8 + 0..7]
    #pragma unroll
    for (int ih2 = 0; ih2 < 4; ++ih2) {     // output rows 8*ih2 .. 8*ih2+7
      f32x4 A = {0.f, 0.f, 0.f, 0.f};
      f32x4 Bv = {0.f, 0.f, 0.f, 0.f};
      #pragma unroll
      for (int e = 0; e < 16; ++e) {
        int r = 16 * h + e;
        float tv = T2[e >> 1][e & 1];
        f32x4 tv4 = {tv, tv, tv, tv};
        A  = fma4(w14[r * 8 + ih2 * 2],     tv4, A);
        Bv = fma4(w14[r * 8 + ih2 * 2 + 1], tv4, Bv);
      }
      A.x += fshfl_xor(A.x, 32);  A.y += fshfl_xor(A.y, 32);
      A.z += fshfl_xor(A.z, 32);  A.w += fshfl_xor(A.w, 32);
      Bv.x += fshfl_xor(Bv.x, 32); Bv.y += fshfl_xor(Bv.y, 32);
      Bv.z += fshfl_xor(Bv.z, 32); Bv.w += fshfl_xor(Bv.w, 32);
      if (h == (ih2 & 1)) {
        *(f32x4*)(Cc + j * 36 + ih2 * 8)     = A;
        *(f32x4*)(Cc + j * 36 + ih2 * 8 + 4) = Bv;
      }
    }
  }
  FENCE();

  // ---------------- load own column half into v2f registers (one-time)
  v2f v1[8];
  {
    const float* bp = Cc + j * 36 + (h << 4);
    f32x4 q0 = *(const f32x4*)(bp);
    f32x4 q1 = *(const f32x4*)(bp + 4);
    f32x4 q2 = *(const f32x4*)(bp + 8);
    f32x4 q3 = *(const f32x4*)(bp + 12);
    v1[0] = q0.lo; v1[1] = q0.hi; v1[2] = q1.lo; v1[3] = q1.hi;
    v1[4] = q2.lo; v1[5] = q2.hi; v1[6] = q3.lo; v1[7] = q3.hi;
  }

  // ---------------- one-sided Jacobi, n=32, register-resident, XOR
  // tournament, incremental norms (refreshed each sweep).
  {
    #pragma unroll 1
    for (int sweep = 0; sweep < 8; ++sweep) {
      // fresh own-norm (kills incremental drift)
      v2f s2n = {0.f, 0.f};
      #pragma unroll
      for (int i = 0; i < 8; ++i) s2n = fma2(v1[i], v1[i], s2n);
      float sn = s2n.x + s2n.y;
      sn += fshfl_xor(sn, 32);

      float offmax = 0.f;
      #pragma unroll 1
      for (int mask = 1; mask < 32; ++mask) {
        const int m = j ^ mask;
        v2f uu[8];
        #pragma unroll
        for (int i = 0; i < 8; ++i) {
          uu[i].x = fshfl_xor(v1[i].x, mask);
          uu[i].y = fshfl_xor(v1[i].y, mask);
        }
        float sb_o = fshfl_xor(sn, mask);    // partner's maintained norm
        v2f sgv = {0.f, 0.f};
        #pragma unroll
        for (int i = 0; i < 8; ++i) sgv = fma2(v1[i], uu[i], sgv);
        float sg = sgv.x + sgv.y;
        sg += fshfl_xor(sg, 32);
        const bool isp = j < m;
        float nA = isp ? sn : sb_o;
        float nB = isp ? sb_o : sn;
        float rel = sg * sg * frcp(fmaxf(nA * nB, 1e-30f));
        offmax = fmaxf(offmax, rel);
        if (rel > 1e-13f) {
          float uc = 0.5f * (nB - nA);
          float R  = fsqrt(uc * uc + sg * sg);
          float t  = sg * frcp(uc + ((uc >= 0.f) ? R : -R));
          float ct = frsq(1.f + t * t);
          float st = ct * t;
          float s  = isp ? -st : st;
          v2f ct2 = {ct, ct}, sv2 = {s, s};
          #pragma unroll
          for (int i = 0; i < 8; ++i)
            v1[i] = fma2(uu[i], sv2, v1[i] * ct2);
          // 2x2 Gram eigenvalue identity: a' = nA - t*sg, b' = nB + t*sg
          sn = fmaxf(isp ? (nA - t * sg) : (nB + t * sg), 0.f);
        }
      }
      #pragma unroll
      for (int mm = 1; mm <= 32; mm <<= 1) offmax = fmaxf(offmax, fshfl_xor(offmax, mm));
      if (offmax < 1e-11f) break;
    }
  }

  // ---------------- lambda_1 + ReEig + Ps = sqrt(clamp(lam1))*v1hat^T w2,
  // all from registers (fresh norm); Pt[16][PT_S] transposed (conflict-free).
  // Two statically-unrolled halves with a sched_barrier between: caps the
  // load-hoisting spike (16 in-flight w2 f32x4 = 64 VGPRs was the peak
  // demand that forced spills under explicit budgets).
  {
    v2f ssv = {0.f, 0.f};
    #pragma unroll
    for (int i = 0; i < 8; ++i) ssv = fma2(v1[i], v1[i], ssv);
    float ss = ssv.x + ssv.y;
    ss += fshfl_xor(ss, 32);
    float lam = fsqrt(ss);
    float sc1 = (lam > 0.f) ? (fsqrt(fmaxf(lam, 1e-4f)) * frcp(lam)) : 0.f;
    f32x4 acc0 = {0.f,0.f,0.f,0.f}, acc1 = acc0, acc2 = acc0, acc3 = acc0;
    #pragma unroll
    for (int t = 0; t < 4; ++t) {
      int rr = (h << 4) + 2 * t;
      const f32x4* wr0 = (const f32x4*)(w2g + rr * 16);
      const f32x4* wr1 = (const f32x4*)(w2g + (rr + 1) * 16);
      float vx = v1[t].x, vy = v1[t].y;
      f32x4 vx4 = {vx, vx, vx, vx};
      f32x4 vy4 = {vy, vy, vy, vy};
      acc0 = fma4(wr0[0], vx4, acc0); acc1 = fma4(wr0[1], vx4, acc1);
      acc2 = fma4(wr0[2], vx4, acc2); acc3 = fma4(wr0[3], vx4, acc3);
      acc0 = fma4(wr1[0], vy4, acc0); acc1 = fma4(wr1[1], vy4, acc1);
      acc2 = fma4(wr1[2], vy4, acc2); acc3 = fma4(wr1[3], vy4, acc3);
    }
    __builtin_amdgcn_sched_barrier(0);   // don't hoist 2nd-half loads above
    #pragma unroll
    for (int t = 4; t < 8; ++t) {
      int rr = (h << 4) + 2 * t;
      const f32x4* wr0 = (const f32x4*)(w2g + rr * 16);
      const f32x4* wr1 = (const f32x4*)(w2g + (rr + 1) * 16);
      float vx = v1[t].x, vy = v1[t].y;
      f32x4 vx4 = {vx, vx, vx, vx};
      f32x4 vy4 = {vy, vy, vy, vy};
      acc0 = fma4(wr0[0], vx4, acc0); acc1 = fma4(wr0[1], vx4, acc1);
      acc2 = fma4(wr0[2], vx4, acc2); acc3 = fma4(wr0[3], vx4, acc3);
      acc0 = fma4(wr1[0], vy4, acc0); acc1 = fma4(wr1[1], vy4, acc1);
      acc2 = fma4(wr1[2], vy4, acc2); acc3 = fma4(wr1[3], vy4, acc3);
    }
    acc0.x = (acc0.x + fshfl_xor(acc0.x, 32)) * sc1;
    acc0.y = (acc0.y + fshfl_xor(acc0.y, 32)) * sc1;
    acc0.z = (acc0.z + fshfl_xor(acc0.z, 32)) * sc1;
    acc0.w = (acc0.w + fshfl_xor(acc0.w, 32)) * sc1;
    acc1.x = (acc1.x + fshfl_xor(acc1.x, 32)) * sc1;
    acc1.y = (acc1.y + fshfl_xor(acc1.y, 32)) * sc1;
    acc1.z = (acc1.z + fshfl_xor(acc1.z, 32)) * sc1;
    acc1.w = (acc1.w + fshfl_xor(acc1.w, 32)) * sc1;
    acc2.x = (acc2.x + fshfl_xor(acc2.x, 32)) * sc1;
    acc2.y = (acc2.y + fshfl_xor(acc2.y, 32)) * sc1;
    acc2.z = (acc2.z + fshfl_xor(acc2.z, 32)) * sc1;
    acc2.w = (acc2.w + fshfl_xor(acc2.w, 32)) * sc1;
    acc3.x = (acc3.x + fshfl_xor(acc3.x, 32)) * sc1;
    acc3.y = (acc3.y + fshfl_xor(acc3.y, 32)) * sc1;
    acc3.z = (acc3.z + fshfl_xor(acc3.z, 32)) * sc1;
    acc3.w = (acc3.w + fshfl_xor(acc3.w, 32)) * sc1;
    // lane (j,h) stores Ps[j][8h..8h+7]: h=0 -> acc0/acc1, h=1 -> acc2/acc3
    f32x4 lo = h ? acc2 : acc0;
    f32x4 hi = h ? acc3 : acc1;
    const int jb8 = h << 3;
    Pt[(jb8 + 0) * PT_S + j] = lo.x;
    Pt[(jb8 + 1) * PT_S + j] = lo.y;
    Pt[(jb8 + 2) * PT_S + j] = lo.z;
    Pt[(jb8 + 3) * PT_S + j] = lo.w;
    Pt[(jb8 + 4) * PT_S + j] = hi.x;
    Pt[(jb8 + 5) * PT_S + j] = hi.y;
    Pt[(jb8 + 6) * PT_S + j] = hi.z;
    Pt[(jb8 + 7) * PT_S + j] = hi.w;
  }
  FENCE();

  // ---------------- M2 = Ps^T Ps directly into stage-2 registers.
  // lane = c2 + 16*h4 owns rows 4h4..4h4+3 of M2 column c2.
  // (kk-loop unroll 2 safe: only LDS pointers use kk.)
  const int c2 = lane & 15;
  const int h4 = lane >> 4;
  f32x4 v2r;
  {
    v2f a0 = {0.f,0.f}, a1 = {0.f,0.f}, a2 = {0.f,0.f}, a3 = {0.f,0.f};
    #pragma unroll 2
    for (int kk = 0; kk < 32; kk += 4) {
      f32x4 aa = *(const f32x4*)(Pt + c2 * PT_S + kk);
      f32x4 b0 = *(const f32x4*)(Pt + (4 * h4 + 0) * PT_S + kk);
      f32x4 b1 = *(const f32x4*)(Pt + (4 * h4 + 1) * PT_S + kk);
      f32x4 b2 = *(const f32x4*)(Pt + (4 * h4 + 2) * PT_S + kk);
      f32x4 b3 = *(const f32x4*)(Pt + (4 * h4 + 3) * PT_S + kk);
      a0 = fma2(aa.lo, b0.lo, a0); a0 = fma2(aa.hi, b0.hi, a0);
      a1 = fma2(aa.lo, b1.lo, a1); a1 = fma2(aa.hi, b1.hi, a1);
      a2 = fma2(aa.lo, b2.lo, a2); a2 = fma2(aa.hi, b2.hi, a2);
      a3 = fma2(aa.lo, b3.lo, a3); a3 = fma2(aa.hi, b3.hi, a3);
    }
    v2r.x = a0.x + a0.y;
    v2r.y = a1.x + a1.y;
    v2r.z = a2.x + a2.y;
    v2r.w = a3.x + a3.y;
  }

  // ---------------- one-sided Jacobi, n=16, register-resident, XOR
  // tournament, incremental norms.
  {
    #pragma unroll 1
    for (int sweep = 0; sweep < 6; ++sweep) {
      v2f sp = fma2(v2r.hi, v2r.hi, v2r.lo * v2r.lo);
      float sn2 = sp.x + sp.y;
      sn2 += fshfl_xor(sn2, 16);
      sn2 += fshfl_xor(sn2, 32);
      float offmax = 0.f;
      #pragma unroll 1
      for (int mask = 1; mask < 16; ++mask) {
        const int m = c2 ^ mask;
        float u0 = fshfl_xor(v2r.x, mask);
        float u1 = fshfl_xor(v2r.y, mask);
        float u2 = fshfl_xor(v2r.z, mask);
        float u3 = fshfl_xor(v2r.w, mask);
        float sb_o = fshfl_xor(sn2, mask);
        v2f ua = {u0, u1}, ub = {u2, u3};
        v2f sgv = fma2(v2r.hi, ub, v2r.lo * ua);
        float sg = sgv.x + sgv.y;
        sg += fshfl_xor(sg, 16);
        sg += fshfl_xor(sg, 32);
        const bool isp = c2 < m;
        float nA = isp ? sn2 : sb_o;
        float nB = isp ? sb_o : sn2;
        float rel = sg * sg * frcp(fmaxf(nA * nB, 1e-30f));
        offmax = fmaxf(offmax, rel);
        if (rel > 1e-13f) {
          float uc = 0.5f * (nB - nA);
          float R  = fsqrt(uc * uc + sg * sg);
          float t  = sg * frcp(uc + ((uc >= 0.f) ? R : -R));
          float ct = frsq(1.f + t * t);
          float st = ct * t;
          float s  = isp ? -st : st;
          f32x4 ct4 = {ct, ct, ct, ct};
          f32x4 s4  = {s, s, s, s};
          f32x4 uu4 = {u0, u1, u2, u3};
          v2r = fma4(uu4, s4, v2r * ct4);
          sn2 = fmaxf(isp ? (nA - t * sg) : (nB + t * sg), 0.f);
        }
      }
      #pragma unroll
      for (int mm = 1; mm <= 32; mm <<= 1) offmax = fmaxf(offmax, fshfl_xor(offmax, mm));
      if (offmax < 1e-11f) break;
    }
  }

  // ---------------- Qb row c2 = (V2^T w3)[c2][:] * sqrt(clamp(lam2)) from regs
  {
    f32x4 qq = {0.f, 0.f, 0.f, 0.f};
    f32x4 w0 = *(const f32x4*)(w3g + (4 * h4 + 0) * 4);
    f32x4 w1r = *(const f32x4*)(w3g + (4 * h4 + 1) * 4);
    f32x4 w2r = *(const f32x4*)(w3g + (4 * h4 + 2) * 4);
    f32x4 w3r = *(const f32x4*)(w3g + (4 * h4 + 3) * 4);
    f32x4 vv0 = {v2r.x, v2r.x, v2r.x, v2r.x};
    f32x4 vv1 = {v2r.y, v2r.y, v2r.y, v2r.y};
    f32x4 vv2 = {v2r.z, v2r.z, v2r.z, v2r.z};
    f32x4 vv3 = {v2r.w, v2r.w, v2r.w, v2r.w};
    qq = fma4(w0, vv0, qq); qq = fma4(w1r, vv1, qq);
    qq = fma4(w2r, vv2, qq); qq = fma4(w3r, vv3, qq);
    v2f sp = fma2(v2r.hi, v2r.hi, v2r.lo * v2r.lo);
    float ssp = sp.x + sp.y;
    float q0 = qq.x, q1 = qq.y, q2 = qq.z, q3 = qq.w;
    q0 += fshfl_xor(q0, 16); q0 += fshfl_xor(q0, 32);
    q1 += fshfl_xor(q1, 16); q1 += fshfl_xor(q1, 32);
    q2 += fshfl_xor(q2, 16); q2 += fshfl_xor(q2, 32);
    q3 += fshfl_xor(q3, 16); q3 += fshfl_xor(q3, 32);
    ssp += fshfl_xor(ssp, 16); ssp += fshfl_xor(ssp, 32);
    float lam = fsqrt(ssp);
    float scl = (lam > 0.f) ? (frcp(lam) * fsqrt(fmaxf(lam, 1e-4f))) : 0.f;
    if (h4 == 0)
      *(f32x4*)(Cc + c2 * 4) = (f32x4){q0 * scl, q1 * scl, q2 * scl, q3 * scl};
  }
  FENCE();

  // ---------------- stage 3: one-sided Jacobi ON THE 16x4 FACTOR, with
  // accumulated rotations J (eigenvectors of M3 = Q^T Q). 5 sweeps.
  float qv = Cc[lane];            // Qb[kq][jq], kq*4+jq == lane
  const int kq = lane >> 2;
  const int jq = lane & 3;
  float jv = (kq == jq) ? 1.f : 0.f;
  {
    #define ROT3(P_, Q_) do {                                             \
      float w_ = fshfl_xor(qv, (P_) ^ (Q_));                              \
      float s1 = qv * qv, s2 = w_ * w_, s3 = qv * w_;                     \
      s1 += fshfl_xor(s1, 4);  s2 += fshfl_xor(s2, 4);  s3 += fshfl_xor(s3, 4);  \
      s1 += fshfl_xor(s1, 8);  s2 += fshfl_xor(s2, 8);  s3 += fshfl_xor(s3, 8);  \
      s1 += fshfl_xor(s1, 16); s2 += fshfl_xor(s2, 16); s3 += fshfl_xor(s3, 16); \
      s1 += fshfl_xor(s1, 32); s2 += fshfl_xor(s2, 32); s3 += fshfl_xor(s3, 32); \
      bool isp = (jq == (P_)), isq = (jq == (Q_));                        \
      float sa = isp ? s1 : s2;                                           \
      float sb = isp ? s2 : s1;                                           \
      float u_ = 0.5f * (sb - sa);                                        \
      float R_ = fsqrt(u_ * u_ + s3 * s3);                                \
      float dn_ = u_ + copysignf(fmaxf(R_, 1e-30f), u_);                  \
      float t_ = s3 * frcp(dn_);                                          \
      float ct = frsq(1.f + t_ * t_);                                     \
      float st = ct * t_;                                                 \
      float wj_ = fshfl_xor(jv, (P_) ^ (Q_));                             \
      float nv  = isp ? (ct * qv - st * w_)  : (st * w_  + ct * qv);      \
      float nvj = isp ? (ct * jv - st * wj_) : (st * wj_ + ct * jv);      \
      if (isp | isq) { qv = nv; jv = nvj; }                               \
    } while (0)

    #pragma unroll 1
    for (int sweep = 0; sweep < 5; ++sweep) {
      ROT3(0,1); ROT3(2,3); ROT3(0,2); ROT3(1,3); ROT3(0,3); ROT3(1,2);
    }
    #undef ROT3
  }

  // ---------------- lambda_3 = ||col||^2, LogEig via J, FC, log_softmax
  {
    float ss = qv * qv;
    ss += fshfl_xor(ss, 4); ss += fshfl_xor(ss, 8);
    ss += fshfl_xor(ss, 16); ss += fshfl_xor(ss, 32);
    float lwv = logf(fmaxf(ss, 1e-10f));       // log eigenvalue of column jq
    if (kq < 4)  Cc[64 + kq * 4 + jq] = jv;    // J, row-major 4x4
    if (kq == 0) Cc[80 + jq] = lwv;            // lanes 0..3: per-column loglam
    FENCE();

    float f = 0.f;
    if (lane < 16) {
      int i3 = lane >> 2, j3 = lane & 3;
      #pragma unroll
      for (int c = 0; c < 4; ++c)
        f += Cc[80 + c] * Cc[64 + i3 * 4 + c] * Cc[64 + j3 * 4 + c];
    }
    float t0 = 0.f, t1 = 0.f;
    if (lane < 16) { t0 = f * fcg[2 * lane]; t1 = f * fcg[2 * lane + 1]; }
    t0 += fshfl_xor(t0, 1); t1 += fshfl_xor(t1, 1);
    t0 += fshfl_xor(t0, 2); t1 += fshfl_xor(t1, 2);
    t0 += fshfl_xor(t0, 4); t1 += fshfl_xor(t1, 4);
    t0 += fshfl_xor(t0, 8); t1 += fshfl_xor(t1, 8);
    float mx  = fmaxf(t0, t1);
    float lse = mx + logf(expf(t0 - mx) + expf(t1 - mx));

    float* outFeat = outg + (size_t)B * 2;
    if (lane < 16) outFeat[(size_t)b * 16 + lane] = f;
    if (lane < 2)  outg[(size_t)b * 2 + lane] = (lane == 0 ? t0 : t1) - lse;
  }
}

extern "C" void kernel_launch(void* const* d_in, const int* in_sizes, int n_in,
                              void* d_out, int out_size, void* d_ws, size_t ws_size,
                              hipStream_t stream) {
  const float* x  = (const float*)d_in[0];
  const float* w1 = (const float*)d_in[1];
  const float* w2 = (const float*)d_in[2];
  const float* w3 = (const float*)d_in[3];
  const float* fc = (const float*)d_in[4];
  float* out = (float*)d_out;
  int B = in_sizes[0] / 1024;
  int grid = (B + 3) / 4;
  hipLaunchKernelGGL(spd_fused, dim3(grid), dim3(256), 0, stream,
                     x, w1, w2, w3, fc, out, B);
}